// Round 1
// baseline (1013.373 us; speedup 1.0000x reference)
//
#include <hip/hip_runtime.h>

#define NN 50000
#define EE 800000

// ---------------------------------------------------------------------------
// GEMM: out[n][m] = sum_k act(in[n][k]) * W[k][m],  K = M = 128
// act(v) = applyAct ? max(v + bias[k], 0) : v
// block 256: tx = tid&15 -> 8 features (m = tx*8..tx*8+7)
//            ty = tid>>4 -> 4 nodes   (n = ty*4..ty*4+3)
// 64 nodes per block; K processed in two halves of 64 to keep LDS at ~49KB
// (3 blocks/CU). Per 4-k chunk: 4 x-b128 + 8 W-b128 LDS reads, 128 FMA.
// ---------------------------------------------------------------------------
__global__ __launch_bounds__(256, 3) void gemm128(
    const float* __restrict__ in, const float* __restrict__ W,
    const float* __restrict__ bias, float* __restrict__ out,
    int N, int applyAct)
{
    __shared__ float Wl[64 * 128];   // 32 KB (one K-half, all 128 cols)
    __shared__ float Xl[64][68];     // 17 KB (64 nodes x 64 k, +4 pad)

    const int tid = threadIdx.x;
    const int tx = tid & 15;
    const int ty = tid >> 4;
    const int n0 = blockIdx.x * 64;

    float acc[4][8];
#pragma unroll
    for (int j = 0; j < 4; j++)
#pragma unroll
        for (int i = 0; i < 8; i++) acc[j][i] = 0.f;

    for (int half = 0; half < 2; half++) {
        const int k0 = half * 64;
        // stage W half: 8192 floats = 2048 float4, 8 per thread
        {
            const float4* Wg = (const float4*)(W + k0 * 128);
            float4* Ws = (float4*)Wl;
#pragma unroll
            for (int i = 0; i < 8; i++) Ws[tid + i * 256] = Wg[tid + i * 256];
        }
        // stage X tile with activation: 64x64 floats = 1024 float4, 4 per thread
        {
#pragma unroll
            for (int i = 0; i < 4; i++) {
                int idx = tid + i * 256;     // float4 index; 16 per row
                int row = idx >> 4;
                int cg = idx & 15;
                int n = n0 + row;
                float4 v = make_float4(0.f, 0.f, 0.f, 0.f);
                if (n < N) v = *(const float4*)(in + (size_t)n * 128 + k0 + cg * 4);
                if (applyAct) {
                    float4 b = *(const float4*)(bias + k0 + cg * 4);
                    v.x = fmaxf(v.x + b.x, 0.f);
                    v.y = fmaxf(v.y + b.y, 0.f);
                    v.z = fmaxf(v.z + b.z, 0.f);
                    v.w = fmaxf(v.w + b.w, 0.f);
                }
                *(float4*)&Xl[row][cg * 4] = v;
            }
        }
        __syncthreads();

#pragma unroll 2
        for (int kk = 0; kk < 64; kk += 4) {
            float4 xv[4];
#pragma unroll
            for (int j = 0; j < 4; j++) xv[j] = *(const float4*)&Xl[ty * 4 + j][kk];
#pragma unroll
            for (int i = 0; i < 4; i++) {
                const float* wrow = &Wl[(kk + i) * 128 + tx * 8];
                float4 w0 = *(const float4*)(wrow);
                float4 w1 = *(const float4*)(wrow + 4);
#pragma unroll
                for (int j = 0; j < 4; j++) {
                    float xs = ((const float*)&xv[j])[i];
                    acc[j][0] += xs * w0.x; acc[j][1] += xs * w0.y;
                    acc[j][2] += xs * w0.z; acc[j][3] += xs * w0.w;
                    acc[j][4] += xs * w1.x; acc[j][5] += xs * w1.y;
                    acc[j][6] += xs * w1.z; acc[j][7] += xs * w1.w;
                }
            }
        }
        __syncthreads();
    }

#pragma unroll
    for (int j = 0; j < 4; j++) {
        int n = n0 + ty * 4 + j;
        if (n < N) {
            float* op = out + (size_t)n * 128 + tx * 8;
            *(float4*)op = make_float4(acc[j][0], acc[j][1], acc[j][2], acc[j][3]);
            *(float4*)(op + 4) = make_float4(acc[j][4], acc[j][5], acc[j][6], acc[j][7]);
        }
    }
}

// ---------------------------------------------------------------------------
// scatter-add, 128 features: one thread per (edge, feature)
// wave = 64 lanes = one half-row -> coalesced gather + consecutive atomics
// ---------------------------------------------------------------------------
__global__ __launch_bounds__(256) void scatter_add128(
    const float* __restrict__ val, const int* __restrict__ src,
    const int* __restrict__ dst, float* __restrict__ agg, int E)
{
    int gid = blockIdx.x * 256 + threadIdx.x;
    int e = gid >> 7;
    if (e >= E) return;
    int f = gid & 127;
    int s = src[e];
    int d = dst[e];
    float v = val[(size_t)s * 128 + f];
    unsafeAtomicAdd(agg + (size_t)d * 128 + f, v);
}

// ---------------------------------------------------------------------------
// scatter-add, 40 features (input rows padded to stride 128): 6 edges / block
// ---------------------------------------------------------------------------
__global__ __launch_bounds__(256) void scatter_add40(
    const float* __restrict__ val, const int* __restrict__ src,
    const int* __restrict__ dst, float* __restrict__ out, int E)
{
    int t = threadIdx.x;
    if (t >= 240) return;
    int e = blockIdx.x * 6 + t / 40;
    if (e >= E) return;
    int f = t % 40;
    float v = val[(size_t)src[e] * 128 + f];
    unsafeAtomicAdd(out + (size_t)dst[e] * 40 + f, v);
}

// out[n][f] = b2[f]  (final bias as scatter base)
__global__ __launch_bounds__(256) void init_out_bias(
    float* __restrict__ out, const float* __restrict__ b2, int total)
{
    int i = blockIdx.x * 256 + threadIdx.x;
    if (i < total) out[i] = b2[i % 40];
}

// pad W2 (128x40) -> Wp (128x128, zero-filled)
__global__ __launch_bounds__(256) void pad_w2(
    const float* __restrict__ W2, float* __restrict__ Wp)
{
    int i = blockIdx.x * 256 + threadIdx.x;  // 0..16383
    int k = i >> 7;
    int m = i & 127;
    Wp[i] = (m < 40) ? W2[k * 40 + m] : 0.f;
}

extern "C" void kernel_launch(void* const* d_in, const int* in_sizes, int n_in,
                              void* d_out, int out_size, void* d_ws, size_t ws_size,
                              hipStream_t stream)
{
    const float* x  = (const float*)d_in[0];
    const int*   ei = (const int*)d_in[1];
    const float* W0 = (const float*)d_in[2];
    const float* b0 = (const float*)d_in[3];
    const float* W1 = (const float*)d_in[4];
    const float* b1 = (const float*)d_in[5];
    const float* W2 = (const float*)d_in[6];
    const float* b2 = (const float*)d_in[7];
    float* out = (float*)d_out;

    const int N = NN, E = EE;
    const int* src = ei;        // edge_index[0]
    const int* dst = ei + E;    // edge_index[1]

    char* ws = (char*)d_ws;
    float* bufA = (float*)ws;                       // 25.6 MB (tmp = hW)
    float* bufB = (float*)(ws + 25600000);          // 25.6 MB (agg)
    float* Wp   = (float*)(ws + 51200000);          // 64 KB (padded W2)

    const size_t featBytes = (size_t)N * 128 * 4;
    const int gemmGrid = (N + 63) / 64;             // 782
    const int scatGrid = (E * 128) / 256;           // 400000
    const int scat40Grid = (E + 5) / 6;             // 133334

    // ---- layer 0: tmp0 = x @ W0 ; agg0 = scatter(tmp0)
    gemm128<<<gemmGrid, 256, 0, stream>>>(x, W0, nullptr, bufA, N, 0);
    hipMemsetAsync(bufB, 0, featBytes, stream);
    scatter_add128<<<scatGrid, 256, 0, stream>>>(bufA, src, dst, bufB, E);

    // ---- layer 1: tmp1 = relu(agg0 + b0) @ W1 ; agg1 = scatter(tmp1)
    gemm128<<<gemmGrid, 256, 0, stream>>>(bufB, W1, b0, bufA, N, 1);
    hipMemsetAsync(bufB, 0, featBytes, stream);
    scatter_add128<<<scatGrid, 256, 0, stream>>>(bufA, src, dst, bufB, E);

    // ---- layer 2: tmp2 = relu(agg1 + b1) @ W2pad ; out = b2 + scatter(tmp2)
    pad_w2<<<64, 256, 0, stream>>>(W2, Wp);
    gemm128<<<gemmGrid, 256, 0, stream>>>(bufB, Wp, b1, bufA, N, 1);
    init_out_bias<<<(N * 40 + 255) / 256, 256, 0, stream>>>(out, b2, N * 40);
    scatter_add40<<<scat40Grid, 256, 0, stream>>>(bufA, src, dst, out, E);
}

// Round 2
// 521.674 us; speedup vs baseline: 1.9425x; 1.9425x over previous
//
#include <hip/hip_runtime.h>

#define NN 50000
#define EE 800000

// ---------------------------------------------------------------------------
// GEMM: out[n][m] = sum_k act(in[n][k]) * W[k][m],  K = M = 128
// act(v) = applyAct ? max(v + bias[k], 0) : v
// ---------------------------------------------------------------------------
__global__ __launch_bounds__(256, 3) void gemm128(
    const float* __restrict__ in, const float* __restrict__ W,
    const float* __restrict__ bias, float* __restrict__ out,
    int N, int applyAct)
{
    __shared__ float Wl[64 * 128];   // 32 KB (one K-half, all 128 cols)
    __shared__ float Xl[64][68];     // 17 KB (64 nodes x 64 k, +4 pad)

    const int tid = threadIdx.x;
    const int tx = tid & 15;
    const int ty = tid >> 4;
    const int n0 = blockIdx.x * 64;

    float acc[4][8];
#pragma unroll
    for (int j = 0; j < 4; j++)
#pragma unroll
        for (int i = 0; i < 8; i++) acc[j][i] = 0.f;

    for (int half = 0; half < 2; half++) {
        const int k0 = half * 64;
        {
            const float4* Wg = (const float4*)(W + k0 * 128);
            float4* Ws = (float4*)Wl;
#pragma unroll
            for (int i = 0; i < 8; i++) Ws[tid + i * 256] = Wg[tid + i * 256];
        }
        {
#pragma unroll
            for (int i = 0; i < 4; i++) {
                int idx = tid + i * 256;     // float4 index; 16 per row
                int row = idx >> 4;
                int cg = idx & 15;
                int n = n0 + row;
                float4 v = make_float4(0.f, 0.f, 0.f, 0.f);
                if (n < N) v = *(const float4*)(in + (size_t)n * 128 + k0 + cg * 4);
                if (applyAct) {
                    float4 b = *(const float4*)(bias + k0 + cg * 4);
                    v.x = fmaxf(v.x + b.x, 0.f);
                    v.y = fmaxf(v.y + b.y, 0.f);
                    v.z = fmaxf(v.z + b.z, 0.f);
                    v.w = fmaxf(v.w + b.w, 0.f);
                }
                *(float4*)&Xl[row][cg * 4] = v;
            }
        }
        __syncthreads();

#pragma unroll 2
        for (int kk = 0; kk < 64; kk += 4) {
            float4 xv[4];
#pragma unroll
            for (int j = 0; j < 4; j++) xv[j] = *(const float4*)&Xl[ty * 4 + j][kk];
#pragma unroll
            for (int i = 0; i < 4; i++) {
                const float* wrow = &Wl[(kk + i) * 128 + tx * 8];
                float4 w0 = *(const float4*)(wrow);
                float4 w1 = *(const float4*)(wrow + 4);
#pragma unroll
                for (int j = 0; j < 4; j++) {
                    float xs = ((const float*)&xv[j])[i];
                    acc[j][0] += xs * w0.x; acc[j][1] += xs * w0.y;
                    acc[j][2] += xs * w0.z; acc[j][3] += xs * w0.w;
                    acc[j][4] += xs * w1.x; acc[j][5] += xs * w1.y;
                    acc[j][6] += xs * w1.z; acc[j][7] += xs * w1.w;
                }
            }
        }
        __syncthreads();
    }

#pragma unroll
    for (int j = 0; j < 4; j++) {
        int n = n0 + ty * 4 + j;
        if (n < N) {
            float* op = out + (size_t)n * 128 + tx * 8;
            *(float4*)op = make_float4(acc[j][0], acc[j][1], acc[j][2], acc[j][3]);
            *(float4*)(op + 4) = make_float4(acc[j][4], acc[j][5], acc[j][6], acc[j][7]);
        }
    }
}

// ---------------------------------------------------------------------------
// CSR build: histogram -> single-block scan -> fill
// ---------------------------------------------------------------------------
__global__ __launch_bounds__(256) void build_deg(
    const int* __restrict__ dst, int* __restrict__ deg, int E)
{
    int e = blockIdx.x * 256 + threadIdx.x;
    if (e < E) atomicAdd(&deg[dst[e]], 1);
}

__global__ __launch_bounds__(1024) void scan_deg(
    const int* __restrict__ deg, int* __restrict__ off,
    int* __restrict__ cursor, int N, int E)
{
    __shared__ int sums[1024];
    const int t = threadIdx.x;
    const int CH = (N + 1023) / 1024;          // 49
    const int base = t * CH;
    int s = 0;
    for (int i = 0; i < CH; i++) {
        int idx = base + i;
        if (idx < N) s += deg[idx];
    }
    sums[t] = s;
    __syncthreads();
    // Hillis-Steele inclusive scan over 1024 partials
    for (int d = 1; d < 1024; d <<= 1) {
        int v = (t >= d) ? sums[t - d] : 0;
        __syncthreads();
        sums[t] += v;
        __syncthreads();
    }
    int run = (t == 0) ? 0 : sums[t - 1];      // exclusive prefix of chunk
    for (int i = 0; i < CH; i++) {
        int idx = base + i;
        if (idx < N) {
            off[idx] = run;
            cursor[idx] = run;
            run += deg[idx];
        }
    }
    if (t == 0) off[N] = E;
}

__global__ __launch_bounds__(256) void fill_csr(
    const int* __restrict__ src, const int* __restrict__ dst,
    int* __restrict__ cursor, int* __restrict__ csr_src, int E)
{
    int e = blockIdx.x * 256 + threadIdx.x;
    if (e >= E) return;
    int pos = atomicAdd(&cursor[dst[e]], 1);
    csr_src[pos] = src[e];
}

// ---------------------------------------------------------------------------
// aggregate, 128 feats: 32 lanes x float4 per node, 8 nodes per block
// ---------------------------------------------------------------------------
__global__ __launch_bounds__(256) void agg128(
    const float* __restrict__ val, const int* __restrict__ off,
    const int* __restrict__ csr_src, float* __restrict__ out, int N)
{
    const int c = threadIdx.x & 31;                  // float4 chunk 0..31
    const int node = blockIdx.x * 8 + (threadIdx.x >> 5);
    if (node >= N) return;
    const int beg = off[node], end = off[node + 1];

    float4 a0 = make_float4(0.f, 0.f, 0.f, 0.f);
    float4 a1 = make_float4(0.f, 0.f, 0.f, 0.f);
    int i = beg;
    for (; i + 1 < end; i += 2) {
        int s0 = csr_src[i];
        int s1 = csr_src[i + 1];
        float4 v0 = *(const float4*)(val + (size_t)s0 * 128 + c * 4);
        float4 v1 = *(const float4*)(val + (size_t)s1 * 128 + c * 4);
        a0.x += v0.x; a0.y += v0.y; a0.z += v0.z; a0.w += v0.w;
        a1.x += v1.x; a1.y += v1.y; a1.z += v1.z; a1.w += v1.w;
    }
    if (i < end) {
        int s0 = csr_src[i];
        float4 v0 = *(const float4*)(val + (size_t)s0 * 128 + c * 4);
        a0.x += v0.x; a0.y += v0.y; a0.z += v0.z; a0.w += v0.w;
    }
    a0.x += a1.x; a0.y += a1.y; a0.z += a1.z; a0.w += a1.w;
    *(float4*)(out + (size_t)node * 128 + c * 4) = a0;
}

// ---------------------------------------------------------------------------
// aggregate, 40 feats (input rows padded to stride 128), + bias b2 -> d_out
// 16 lanes/node (10 active), 16 nodes per block
// ---------------------------------------------------------------------------
__global__ __launch_bounds__(256) void agg40(
    const float* __restrict__ val, const int* __restrict__ off,
    const int* __restrict__ csr_src, const float* __restrict__ b2,
    float* __restrict__ out, int N)
{
    const int c = threadIdx.x & 15;                  // float4 chunk, active < 10
    const int node = blockIdx.x * 16 + (threadIdx.x >> 4);
    if (node >= N || c >= 10) return;
    const int beg = off[node], end = off[node + 1];

    float4 a0 = *(const float4*)(b2 + c * 4);
    float4 a1 = make_float4(0.f, 0.f, 0.f, 0.f);
    int i = beg;
    for (; i + 1 < end; i += 2) {
        int s0 = csr_src[i];
        int s1 = csr_src[i + 1];
        float4 v0 = *(const float4*)(val + (size_t)s0 * 128 + c * 4);
        float4 v1 = *(const float4*)(val + (size_t)s1 * 128 + c * 4);
        a0.x += v0.x; a0.y += v0.y; a0.z += v0.z; a0.w += v0.w;
        a1.x += v1.x; a1.y += v1.y; a1.z += v1.z; a1.w += v1.w;
    }
    if (i < end) {
        int s0 = csr_src[i];
        float4 v0 = *(const float4*)(val + (size_t)s0 * 128 + c * 4);
        a0.x += v0.x; a0.y += v0.y; a0.z += v0.z; a0.w += v0.w;
    }
    a0.x += a1.x; a0.y += a1.y; a0.z += a1.z; a0.w += a1.w;
    *(float4*)(out + (size_t)node * 40 + c * 4) = a0;
}

// pad W2 (128x40) -> Wp (128x128, zero-filled)
__global__ __launch_bounds__(256) void pad_w2(
    const float* __restrict__ W2, float* __restrict__ Wp)
{
    int i = blockIdx.x * 256 + threadIdx.x;  // 0..16383
    int k = i >> 7;
    int m = i & 127;
    Wp[i] = (m < 40) ? W2[k * 40 + m] : 0.f;
}

extern "C" void kernel_launch(void* const* d_in, const int* in_sizes, int n_in,
                              void* d_out, int out_size, void* d_ws, size_t ws_size,
                              hipStream_t stream)
{
    const float* x  = (const float*)d_in[0];
    const int*   ei = (const int*)d_in[1];
    const float* W0 = (const float*)d_in[2];
    const float* b0 = (const float*)d_in[3];
    const float* W1 = (const float*)d_in[4];
    const float* b1 = (const float*)d_in[5];
    const float* W2 = (const float*)d_in[6];
    const float* b2 = (const float*)d_in[7];
    float* out = (float*)d_out;

    const int N = NN, E = EE;
    const int* src = ei;        // edge_index[0]
    const int* dst = ei + E;    // edge_index[1]

    char* ws = (char*)d_ws;
    float* bufA    = (float*)ws;                        // 25.6 MB (tmp = hW)
    float* bufB    = (float*)(ws + 25600000);           // 25.6 MB (agg)
    float* Wp      = (float*)(ws + 51200000);           // 64 KB (padded W2)
    int*   deg     = (int*)  (ws + 51265536);           // 200 KB
    int*   off     = (int*)  (ws + 51470336);           // 200 KB (N+1 ints)
    int*   cursor  = (int*)  (ws + 51675136);           // 200 KB
    int*   csr_src = (int*)  (ws + 51879936);           // 3.2 MB
                                                        // total ~55.1 MB

    const int gemmGrid = (N + 63) / 64;                 // 782
    const int eGrid = (E + 255) / 256;                  // 3125

    // ---- CSR build (once per call, reused by all 3 layers)
    hipMemsetAsync(deg, 0, (size_t)N * 4, stream);
    build_deg<<<eGrid, 256, 0, stream>>>(dst, deg, E);
    scan_deg<<<1, 1024, 0, stream>>>(deg, off, cursor, N, E);
    fill_csr<<<eGrid, 256, 0, stream>>>(src, dst, cursor, csr_src, E);

    // ---- layer 0: tmp0 = x @ W0 ; agg0 = gather-sum(tmp0)
    gemm128<<<gemmGrid, 256, 0, stream>>>(x, W0, nullptr, bufA, N, 0);
    agg128<<<(N + 7) / 8, 256, 0, stream>>>(bufA, off, csr_src, bufB, N);

    // ---- layer 1: tmp1 = relu(agg0 + b0) @ W1 ; agg1 = gather-sum(tmp1)
    gemm128<<<gemmGrid, 256, 0, stream>>>(bufB, W1, b0, bufA, N, 1);
    agg128<<<(N + 7) / 8, 256, 0, stream>>>(bufA, off, csr_src, bufB, N);

    // ---- layer 2: tmp2 = relu(agg1 + b1) @ W2pad ; out = b2 + gather-sum(tmp2)
    pad_w2<<<64, 256, 0, stream>>>(W2, Wp);
    gemm128<<<gemmGrid, 256, 0, stream>>>(bufB, Wp, b1, bufA, N, 1);
    agg40<<<(N + 15) / 16, 256, 0, stream>>>(bufA, off, csr_src, b2, out, N);
}

// Round 3
// 405.342 us; speedup vs baseline: 2.5000x; 1.2870x over previous
//
#include <hip/hip_runtime.h>

#define NN 50000
#define EE 800000

// ---------------------------------------------------------------------------
// GEMM: out[n][m] = sum_k act(in[n][k]) * W[k][m],  K = M = 128
// act(v) = applyAct ? max(v + bias[k], 0) : v
// ---------------------------------------------------------------------------
__global__ __launch_bounds__(256, 3) void gemm128(
    const float* __restrict__ in, const float* __restrict__ W,
    const float* __restrict__ bias, float* __restrict__ out,
    int N, int applyAct)
{
    __shared__ float Wl[64 * 128];   // 32 KB (one K-half, all 128 cols)
    __shared__ float Xl[64][68];     // 17 KB (64 nodes x 64 k, +4 pad)

    const int tid = threadIdx.x;
    const int tx = tid & 15;
    const int ty = tid >> 4;
    const int n0 = blockIdx.x * 64;

    float acc[4][8];
#pragma unroll
    for (int j = 0; j < 4; j++)
#pragma unroll
        for (int i = 0; i < 8; i++) acc[j][i] = 0.f;

    for (int half = 0; half < 2; half++) {
        const int k0 = half * 64;
        {
            const float4* Wg = (const float4*)(W + k0 * 128);
            float4* Ws = (float4*)Wl;
#pragma unroll
            for (int i = 0; i < 8; i++) Ws[tid + i * 256] = Wg[tid + i * 256];
        }
        {
#pragma unroll
            for (int i = 0; i < 4; i++) {
                int idx = tid + i * 256;     // float4 index; 16 per row
                int row = idx >> 4;
                int cg = idx & 15;
                int n = n0 + row;
                float4 v = make_float4(0.f, 0.f, 0.f, 0.f);
                if (n < N) v = *(const float4*)(in + (size_t)n * 128 + k0 + cg * 4);
                if (applyAct) {
                    float4 b = *(const float4*)(bias + k0 + cg * 4);
                    v.x = fmaxf(v.x + b.x, 0.f);
                    v.y = fmaxf(v.y + b.y, 0.f);
                    v.z = fmaxf(v.z + b.z, 0.f);
                    v.w = fmaxf(v.w + b.w, 0.f);
                }
                *(float4*)&Xl[row][cg * 4] = v;
            }
        }
        __syncthreads();

#pragma unroll 2
        for (int kk = 0; kk < 64; kk += 4) {
            float4 xv[4];
#pragma unroll
            for (int j = 0; j < 4; j++) xv[j] = *(const float4*)&Xl[ty * 4 + j][kk];
#pragma unroll
            for (int i = 0; i < 4; i++) {
                const float* wrow = &Wl[(kk + i) * 128 + tx * 8];
                float4 w0 = *(const float4*)(wrow);
                float4 w1 = *(const float4*)(wrow + 4);
#pragma unroll
                for (int j = 0; j < 4; j++) {
                    float xs = ((const float*)&xv[j])[i];
                    acc[j][0] += xs * w0.x; acc[j][1] += xs * w0.y;
                    acc[j][2] += xs * w0.z; acc[j][3] += xs * w0.w;
                    acc[j][4] += xs * w1.x; acc[j][5] += xs * w1.y;
                    acc[j][6] += xs * w1.z; acc[j][7] += xs * w1.w;
                }
            }
        }
        __syncthreads();
    }

#pragma unroll
    for (int j = 0; j < 4; j++) {
        int n = n0 + ty * 4 + j;
        if (n < N) {
            float* op = out + (size_t)n * 128 + tx * 8;
            *(float4*)op = make_float4(acc[j][0], acc[j][1], acc[j][2], acc[j][3]);
            *(float4*)(op + 4) = make_float4(acc[j][4], acc[j][5], acc[j][6], acc[j][7]);
        }
    }
}

// ---------------------------------------------------------------------------
// CSR build: histogram -> multi-block scan -> fill
// ---------------------------------------------------------------------------
__global__ __launch_bounds__(256) void build_deg(
    const int* __restrict__ dst, int* __restrict__ deg, int E)
{
    int e = blockIdx.x * 256 + threadIdx.x;
    if (e < E) atomicAdd(&deg[dst[e]], 1);
}

// phase 1: per-block exclusive scan of 1024 elems, block total -> blockSums
__global__ __launch_bounds__(1024) void block_scan(
    const int* __restrict__ deg, int* __restrict__ off,
    int* __restrict__ blockSums, int N)
{
    __shared__ int sh[1024];
    const int t = threadIdx.x;
    const int idx = blockIdx.x * 1024 + t;
    const int v = (idx < N) ? deg[idx] : 0;
    sh[t] = v;
    __syncthreads();
    for (int d = 1; d < 1024; d <<= 1) {
        int u = (t >= d) ? sh[t - d] : 0;
        __syncthreads();
        sh[t] += u;
        __syncthreads();
    }
    if (idx < N) off[idx] = sh[t] - v;            // local exclusive prefix
    if (t == 1023) blockSums[blockIdx.x] = sh[t]; // block total
}

// phase 2: exclusive scan of block totals (nb <= 64) in one wave
__global__ __launch_bounds__(64) void scan_sums(
    int* __restrict__ blockSums, int nb)
{
    const int t = threadIdx.x;
    const int orig = (t < nb) ? blockSums[t] : 0;
    int v = orig;
#pragma unroll
    for (int d = 1; d < 64; d <<= 1) {
        int u = __shfl_up(v, d);
        if (t >= d) v += u;
    }
    if (t < nb) blockSums[t] = v - orig;          // exclusive
}

// phase 3: add block offsets, materialize off + cursor, set off[N]=E
__global__ __launch_bounds__(1024) void add_offsets(
    int* __restrict__ off, int* __restrict__ cursor,
    const int* __restrict__ blockSums, int N, int E)
{
    const int idx = blockIdx.x * 1024 + threadIdx.x;
    if (idx < N) {
        int o = off[idx] + blockSums[blockIdx.x];
        off[idx] = o;
        cursor[idx] = o;
    }
    if (idx == 0) off[N] = E;
}

__global__ __launch_bounds__(256) void fill_csr(
    const int* __restrict__ src, const int* __restrict__ dst,
    int* __restrict__ cursor, int* __restrict__ csr_src, int E)
{
    int e = blockIdx.x * 256 + threadIdx.x;
    if (e >= E) return;
    int pos = atomicAdd(&cursor[dst[e]], 1);
    csr_src[pos] = src[e];
}

// ---------------------------------------------------------------------------
// aggregate, 128 feats: 32 lanes x float4 per node, 8 nodes per block
// ---------------------------------------------------------------------------
__global__ __launch_bounds__(256) void agg128(
    const float* __restrict__ val, const int* __restrict__ off,
    const int* __restrict__ csr_src, float* __restrict__ out, int N)
{
    const int c = threadIdx.x & 31;                  // float4 chunk 0..31
    const int node = blockIdx.x * 8 + (threadIdx.x >> 5);
    if (node >= N) return;
    const int beg = off[node], end = off[node + 1];

    float4 a0 = make_float4(0.f, 0.f, 0.f, 0.f);
    float4 a1 = make_float4(0.f, 0.f, 0.f, 0.f);
    int i = beg;
    for (; i + 1 < end; i += 2) {
        int s0 = csr_src[i];
        int s1 = csr_src[i + 1];
        float4 v0 = *(const float4*)(val + (size_t)s0 * 128 + c * 4);
        float4 v1 = *(const float4*)(val + (size_t)s1 * 128 + c * 4);
        a0.x += v0.x; a0.y += v0.y; a0.z += v0.z; a0.w += v0.w;
        a1.x += v1.x; a1.y += v1.y; a1.z += v1.z; a1.w += v1.w;
    }
    if (i < end) {
        int s0 = csr_src[i];
        float4 v0 = *(const float4*)(val + (size_t)s0 * 128 + c * 4);
        a0.x += v0.x; a0.y += v0.y; a0.z += v0.z; a0.w += v0.w;
    }
    a0.x += a1.x; a0.y += a1.y; a0.z += a1.z; a0.w += a1.w;
    *(float4*)(out + (size_t)node * 128 + c * 4) = a0;
}

// ---------------------------------------------------------------------------
// aggregate, 40 feats (input rows padded to stride 128), + bias b2 -> d_out
// ---------------------------------------------------------------------------
__global__ __launch_bounds__(256) void agg40(
    const float* __restrict__ val, const int* __restrict__ off,
    const int* __restrict__ csr_src, const float* __restrict__ b2,
    float* __restrict__ out, int N)
{
    const int c = threadIdx.x & 15;                  // float4 chunk, active < 10
    const int node = blockIdx.x * 16 + (threadIdx.x >> 4);
    if (node >= N || c >= 10) return;
    const int beg = off[node], end = off[node + 1];

    float4 a0 = *(const float4*)(b2 + c * 4);
    float4 a1 = make_float4(0.f, 0.f, 0.f, 0.f);
    int i = beg;
    for (; i + 1 < end; i += 2) {
        int s0 = csr_src[i];
        int s1 = csr_src[i + 1];
        float4 v0 = *(const float4*)(val + (size_t)s0 * 128 + c * 4);
        float4 v1 = *(const float4*)(val + (size_t)s1 * 128 + c * 4);
        a0.x += v0.x; a0.y += v0.y; a0.z += v0.z; a0.w += v0.w;
        a1.x += v1.x; a1.y += v1.y; a1.z += v1.z; a1.w += v1.w;
    }
    if (i < end) {
        int s0 = csr_src[i];
        float4 v0 = *(const float4*)(val + (size_t)s0 * 128 + c * 4);
        a0.x += v0.x; a0.y += v0.y; a0.z += v0.z; a0.w += v0.w;
    }
    a0.x += a1.x; a0.y += a1.y; a0.z += a1.z; a0.w += a1.w;
    *(float4*)(out + (size_t)node * 40 + c * 4) = a0;
}

// pad W2 (128x40) -> Wp (128x128, zero-filled)
__global__ __launch_bounds__(256) void pad_w2(
    const float* __restrict__ W2, float* __restrict__ Wp)
{
    int i = blockIdx.x * 256 + threadIdx.x;  // 0..16383
    int k = i >> 7;
    int m = i & 127;
    Wp[i] = (m < 40) ? W2[k * 40 + m] : 0.f;
}

extern "C" void kernel_launch(void* const* d_in, const int* in_sizes, int n_in,
                              void* d_out, int out_size, void* d_ws, size_t ws_size,
                              hipStream_t stream)
{
    const float* x  = (const float*)d_in[0];
    const int*   ei = (const int*)d_in[1];
    const float* W0 = (const float*)d_in[2];
    const float* b0 = (const float*)d_in[3];
    const float* W1 = (const float*)d_in[4];
    const float* b1 = (const float*)d_in[5];
    const float* W2 = (const float*)d_in[6];
    const float* b2 = (const float*)d_in[7];
    float* out = (float*)d_out;

    const int N = NN, E = EE;
    const int* src = ei;        // edge_index[0]
    const int* dst = ei + E;    // edge_index[1]

    char* ws = (char*)d_ws;
    float* bufA     = (float*)ws;                        // 25.6 MB (tmp = hW)
    float* bufB     = (float*)(ws + 25600000);           // 25.6 MB (agg)
    float* Wp       = (float*)(ws + 51200000);           // 64 KB (padded W2)
    int*   deg      = (int*)  (ws + 51265536);           // 200 KB
    int*   off      = (int*)  (ws + 51470336);           // 200 KB (N+1 ints)
    int*   cursor   = (int*)  (ws + 51675136);           // 200 KB
    int*   csr_src  = (int*)  (ws + 51879936);           // 3.2 MB
    int*   blkSums  = (int*)  (ws + 55079936);           // 256 B (49 ints)
                                                         // total ~55.1 MB

    const int gemmGrid = (N + 63) / 64;                 // 782
    const int eGrid = (E + 255) / 256;                  // 3125
    const int nScanBlocks = (N + 1023) / 1024;          // 49

    // ---- CSR build (once per call, reused by all 3 layers)
    hipMemsetAsync(deg, 0, (size_t)N * 4, stream);
    build_deg<<<eGrid, 256, 0, stream>>>(dst, deg, E);
    block_scan<<<nScanBlocks, 1024, 0, stream>>>(deg, off, blkSums, N);
    scan_sums<<<1, 64, 0, stream>>>(blkSums, nScanBlocks);
    add_offsets<<<nScanBlocks, 1024, 0, stream>>>(off, cursor, blkSums, N, E);
    fill_csr<<<eGrid, 256, 0, stream>>>(src, dst, cursor, csr_src, E);

    // ---- layer 0: tmp0 = x @ W0 ; agg0 = gather-sum(tmp0)
    gemm128<<<gemmGrid, 256, 0, stream>>>(x, W0, nullptr, bufA, N, 0);
    agg128<<<(N + 7) / 8, 256, 0, stream>>>(bufA, off, csr_src, bufB, N);

    // ---- layer 1: tmp1 = relu(agg0 + b0) @ W1 ; agg1 = gather-sum(tmp1)
    gemm128<<<gemmGrid, 256, 0, stream>>>(bufB, W1, b0, bufA, N, 1);
    agg128<<<(N + 7) / 8, 256, 0, stream>>>(bufA, off, csr_src, bufB, N);

    // ---- layer 2: tmp2 = relu(agg1 + b1) @ W2pad ; out = b2 + gather-sum(tmp2)
    pad_w2<<<64, 256, 0, stream>>>(W2, Wp);
    gemm128<<<gemmGrid, 256, 0, stream>>>(bufB, Wp, b1, bufA, N, 1);
    agg40<<<(N + 15) / 16, 256, 0, stream>>>(bufA, off, csr_src, b2, out, N);
}

// Round 4
// 308.533 us; speedup vs baseline: 3.2845x; 1.3138x over previous
//
#include <hip/hip_runtime.h>

#define NN 50000
#define EE 800000

typedef unsigned short u16;
typedef __attribute__((ext_vector_type(8))) short short8;   // 8 bf16 (4 VGPRs)
typedef __attribute__((ext_vector_type(4))) float f32x4;
typedef __attribute__((ext_vector_type(4))) unsigned short ushort4v;

__device__ __forceinline__ float b2f(u16 u) {
    return __uint_as_float(((unsigned)u) << 16);
}
__device__ __forceinline__ u16 f2b(float f) {
    unsigned u = __float_as_uint(f);
    return (u16)((u + 0x7FFF + ((u >> 16) & 1)) >> 16);   // RNE
}

// ---------------------------------------------------------------------------
// convert x (fp32) -> bf16, stride 128 unchanged
// ---------------------------------------------------------------------------
__global__ __launch_bounds__(256) void conv_x(
    const float* __restrict__ x, u16* __restrict__ xb, int total)
{
    int i = (blockIdx.x * 256 + threadIdx.x) * 4;
    if (i >= total) return;
    float4 v = *(const float4*)(x + i);
    ushort4v o;
    o.x = f2b(v.x); o.y = f2b(v.y); o.z = f2b(v.z); o.w = f2b(v.w);
    *(ushort4v*)(xb + i) = o;
}

// ---------------------------------------------------------------------------
// pack W0/W1/W2(padded) into MFMA B-fragment order (bf16):
// Wf[set][ (nt*4+kt)*64 + lane ][j] = W[k][n],
//   k = kt*32 + (lane>>4)*8 + j, n = nt*16 + (lane&15)
// grid: set*32 + nt*4 + kt  (96 blocks x 64 threads)
// ---------------------------------------------------------------------------
__global__ __launch_bounds__(64) void prep_w(
    const float* __restrict__ W0, const float* __restrict__ W1,
    const float* __restrict__ W2, u16* __restrict__ Wf)
{
    int b = blockIdx.x;
    int set = b >> 5, nt = (b >> 2) & 7, kt = b & 3;
    int lane = threadIdx.x;
    const float* W = (set == 0) ? W0 : (set == 1) ? W1 : W2;
    int ld = (set == 2) ? 40 : 128;
    int ncols = (set == 2) ? 40 : 128;
    int n = nt * 16 + (lane & 15);
    int kbase = kt * 32 + (lane >> 4) * 8;
    u16* dst = Wf + set * 16384 + (size_t)((nt * 4 + kt) * 64 + lane) * 8;
#pragma unroll
    for (int j = 0; j < 8; j++) {
        float v = (n < ncols) ? W[(kbase + j) * ld + n] : 0.f;
        dst[j] = f2b(v);
    }
}

// ---------------------------------------------------------------------------
// MFMA GEMM: out[n][m] = sum_k A[n][k] * W[k][m], K=M=128, bf16 in/out.
// block = 4 waves, each wave computes a 16x128 strip (8 n-tiles x 4 k-tiles).
// A frag:  A[m=lane&15][k=(lane>>4)*8+j]   (contiguous 16B per lane)
// D frag:  col=lane&15, row=(lane>>4)*4+r  (m89-verified)
// ---------------------------------------------------------------------------
__global__ __launch_bounds__(256) void gemm_mfma(
    const u16* __restrict__ A, const u16* __restrict__ Wf,
    u16* __restrict__ out, int N)
{
    const int wave = threadIdx.x >> 6;
    const int lane = threadIdx.x & 63;
    const int m = lane & 15;
    const int q = lane >> 4;
    const int rowBase = blockIdx.x * 64 + wave * 16;
    const int arow = rowBase + m;
    const bool rowOk = (arow < N);

    short8 af[4];
#pragma unroll
    for (int kt = 0; kt < 4; kt++) {
        if (rowOk)
            af[kt] = *(const short8*)(A + (size_t)arow * 128 + kt * 32 + q * 8);
        else
            af[kt] = (short8)0;
    }

    f32x4 acc[8];
#pragma unroll
    for (int nt = 0; nt < 8; nt++) acc[nt] = (f32x4)0.f;

#pragma unroll
    for (int kt = 0; kt < 4; kt++) {
#pragma unroll
        for (int nt = 0; nt < 8; nt++) {
            short8 bf = *(const short8*)(Wf + (size_t)((nt * 4 + kt) * 64 + lane) * 8);
            acc[nt] = __builtin_amdgcn_mfma_f32_16x16x32_bf16(af[kt], bf, acc[nt], 0, 0, 0);
        }
    }

#pragma unroll
    for (int nt = 0; nt < 8; nt++) {
#pragma unroll
        for (int r = 0; r < 4; r++) {
            int orow = rowBase + q * 4 + r;
            if (orow < N) out[(size_t)orow * 128 + nt * 16 + m] = f2b(acc[nt][r]);
        }
    }
}

// ---------------------------------------------------------------------------
// CSR build: histogram -> multi-block scan -> fill
// ---------------------------------------------------------------------------
__global__ __launch_bounds__(256) void build_deg(
    const int* __restrict__ dst, int* __restrict__ deg, int E)
{
    int e = blockIdx.x * 256 + threadIdx.x;
    if (e < E) atomicAdd(&deg[dst[e]], 1);
}

__global__ __launch_bounds__(1024) void block_scan(
    const int* __restrict__ deg, int* __restrict__ off,
    int* __restrict__ blockSums, int N)
{
    __shared__ int sh[1024];
    const int t = threadIdx.x;
    const int idx = blockIdx.x * 1024 + t;
    const int v = (idx < N) ? deg[idx] : 0;
    sh[t] = v;
    __syncthreads();
    for (int d = 1; d < 1024; d <<= 1) {
        int u = (t >= d) ? sh[t - d] : 0;
        __syncthreads();
        sh[t] += u;
        __syncthreads();
    }
    if (idx < N) off[idx] = sh[t] - v;
    if (t == 1023) blockSums[blockIdx.x] = sh[t];
}

__global__ __launch_bounds__(64) void scan_sums(
    int* __restrict__ blockSums, int nb)
{
    const int t = threadIdx.x;
    const int orig = (t < nb) ? blockSums[t] : 0;
    int v = orig;
#pragma unroll
    for (int d = 1; d < 64; d <<= 1) {
        int u = __shfl_up(v, d);
        if (t >= d) v += u;
    }
    if (t < nb) blockSums[t] = v - orig;
}

__global__ __launch_bounds__(1024) void add_offsets(
    int* __restrict__ off, int* __restrict__ cursor,
    const int* __restrict__ blockSums, int N, int E)
{
    const int idx = blockIdx.x * 1024 + threadIdx.x;
    if (idx < N) {
        int o = off[idx] + blockSums[blockIdx.x];
        off[idx] = o;
        cursor[idx] = o;
    }
    if (idx == 0) off[N] = E;
}

__global__ __launch_bounds__(256) void fill_csr(
    const int* __restrict__ src, const int* __restrict__ dst,
    int* __restrict__ cursor, int* __restrict__ csr_src, int E)
{
    int e = blockIdx.x * 256 + threadIdx.x;
    if (e >= E) return;
    int pos = atomicAdd(&cursor[dst[e]], 1);
    csr_src[pos] = src[e];
}

// ---------------------------------------------------------------------------
// aggregate 128 feats (bf16 rows, fp32 accum) + bias + relu -> bf16
// 16 lanes x 16B per node, 16 nodes per block
// ---------------------------------------------------------------------------
__global__ __launch_bounds__(256) void agg128b(
    const u16* __restrict__ val, const int* __restrict__ off,
    const int* __restrict__ csr_src, const float* __restrict__ bias,
    u16* __restrict__ out, int N)
{
    const int c = threadIdx.x & 15;
    const int node = blockIdx.x * 16 + (threadIdx.x >> 4);
    if (node >= N) return;
    const int beg = off[node], end = off[node + 1];

    float a0[8] = {0, 0, 0, 0, 0, 0, 0, 0};
    float a1[8] = {0, 0, 0, 0, 0, 0, 0, 0};
    int i = beg;
    for (; i + 1 < end; i += 2) {
        int s0 = csr_src[i];
        int s1 = csr_src[i + 1];
        short8 v0 = *(const short8*)(val + (size_t)s0 * 128 + c * 8);
        short8 v1 = *(const short8*)(val + (size_t)s1 * 128 + c * 8);
#pragma unroll
        for (int j = 0; j < 8; j++) {
            a0[j] += b2f((u16)v0[j]);
            a1[j] += b2f((u16)v1[j]);
        }
    }
    if (i < end) {
        int s0 = csr_src[i];
        short8 v0 = *(const short8*)(val + (size_t)s0 * 128 + c * 8);
#pragma unroll
        for (int j = 0; j < 8; j++) a0[j] += b2f((u16)v0[j]);
    }

    float4 bA = *(const float4*)(bias + c * 8);
    float4 bB = *(const float4*)(bias + c * 8 + 4);
    float bb[8] = {bA.x, bA.y, bA.z, bA.w, bB.x, bB.y, bB.z, bB.w};
    short8 o;
#pragma unroll
    for (int j = 0; j < 8; j++)
        o[j] = (short)f2b(fmaxf(a0[j] + a1[j] + bb[j], 0.f));
    *(short8*)(out + (size_t)node * 128 + c * 8) = o;
}

// ---------------------------------------------------------------------------
// aggregate first 40 feats of bf16 stride-128 rows, + b2 -> fp32 d_out
// 16 lanes/node (10 active, ushort4 each), 16 nodes per block
// ---------------------------------------------------------------------------
__global__ __launch_bounds__(256) void agg40b(
    const u16* __restrict__ val, const int* __restrict__ off,
    const int* __restrict__ csr_src, const float* __restrict__ b2,
    float* __restrict__ out, int N)
{
    const int c = threadIdx.x & 15;
    const int node = blockIdx.x * 16 + (threadIdx.x >> 4);
    if (node >= N || c >= 10) return;
    const int beg = off[node], end = off[node + 1];

    float a0[4] = {0, 0, 0, 0};
    float a1[4] = {0, 0, 0, 0};
    int i = beg;
    for (; i + 1 < end; i += 2) {
        int s0 = csr_src[i];
        int s1 = csr_src[i + 1];
        ushort4v v0 = *(const ushort4v*)(val + (size_t)s0 * 128 + c * 4);
        ushort4v v1 = *(const ushort4v*)(val + (size_t)s1 * 128 + c * 4);
        a0[0] += b2f(v0.x); a0[1] += b2f(v0.y); a0[2] += b2f(v0.z); a0[3] += b2f(v0.w);
        a1[0] += b2f(v1.x); a1[1] += b2f(v1.y); a1[2] += b2f(v1.z); a1[3] += b2f(v1.w);
    }
    if (i < end) {
        int s0 = csr_src[i];
        ushort4v v0 = *(const ushort4v*)(val + (size_t)s0 * 128 + c * 4);
        a0[0] += b2f(v0.x); a0[1] += b2f(v0.y); a0[2] += b2f(v0.z); a0[3] += b2f(v0.w);
    }
    float4 b = *(const float4*)(b2 + c * 4);
    float4 r;
    r.x = a0[0] + a1[0] + b.x;
    r.y = a0[1] + a1[1] + b.y;
    r.z = a0[2] + a1[2] + b.z;
    r.w = a0[3] + a1[3] + b.w;
    *(float4*)(out + (size_t)node * 40 + c * 4) = r;
}

extern "C" void kernel_launch(void* const* d_in, const int* in_sizes, int n_in,
                              void* d_out, int out_size, void* d_ws, size_t ws_size,
                              hipStream_t stream)
{
    const float* x  = (const float*)d_in[0];
    const int*   ei = (const int*)d_in[1];
    const float* W0 = (const float*)d_in[2];
    const float* b0 = (const float*)d_in[3];
    const float* W1 = (const float*)d_in[4];
    const float* b1 = (const float*)d_in[5];
    const float* W2 = (const float*)d_in[6];
    const float* b2 = (const float*)d_in[7];
    float* out = (float*)d_out;

    const int N = NN, E = EE;
    const int* src = ei;        // edge_index[0]
    const int* dst = ei + E;    // edge_index[1]

    char* ws = (char*)d_ws;
    u16* xb      = (u16*)ws;                        // 12.8 MB  (x in bf16)
    u16* t       = (u16*)(ws + 12800000);           // 12.8 MB  (GEMM out)
    u16* hb      = (u16*)(ws + 25600000);           // 12.8 MB  (agg out)
    u16* Wf      = (u16*)(ws + 38400000);           // 96 KB (3 frag-packed W)
    int* deg     = (int*)(ws + 38500000);           // 200 KB
    int* off     = (int*)(ws + 38700000);           // 200 KB (N+1)
    int* cursor  = (int*)(ws + 38900004);           // 200 KB
    int* csr_src = (int*)(ws + 39100004);           // 3.2 MB
    int* blkSums = (int*)(ws + 42300004);           // 196 B

    const int eGrid = (E + 255) / 256;              // 3125
    const int nScanBlocks = (N + 1023) / 1024;      // 49
    const int gemmGrid = (N + 63) / 64;             // 782
    const int aggGrid = (N + 15) / 16;              // 3125

    // ---- CSR build (reused by all 3 layers)
    hipMemsetAsync(deg, 0, (size_t)N * 4, stream);
    build_deg<<<eGrid, 256, 0, stream>>>(dst, deg, E);
    block_scan<<<nScanBlocks, 1024, 0, stream>>>(deg, off, blkSums, N);
    scan_sums<<<1, 64, 0, stream>>>(blkSums, nScanBlocks);
    add_offsets<<<nScanBlocks, 1024, 0, stream>>>(off, cursor, blkSums, N, E);
    fill_csr<<<eGrid, 256, 0, stream>>>(src, dst, cursor, csr_src, E);

    // ---- precision prep
    conv_x<<<(N * 128 / 4 + 255) / 256, 256, 0, stream>>>(x, xb, N * 128);
    prep_w<<<96, 64, 0, stream>>>(W0, W1, W2, Wf);

    // ---- layer 0: t = xb @ W0 ; hb = relu(agg(t) + b0)
    gemm_mfma<<<gemmGrid, 256, 0, stream>>>(xb, Wf, t, N);
    agg128b<<<aggGrid, 256, 0, stream>>>(t, off, csr_src, b0, hb, N);

    // ---- layer 1: t = hb @ W1 ; hb = relu(agg(t) + b1)
    gemm_mfma<<<gemmGrid, 256, 0, stream>>>(hb, Wf + 16384, t, N);
    agg128b<<<aggGrid, 256, 0, stream>>>(t, off, csr_src, b1, hb, N);

    // ---- layer 2: t = hb @ W2pad ; out = agg40(t) + b2
    gemm_mfma<<<gemmGrid, 256, 0, stream>>>(hb, Wf + 32768, t, N);
    agg40b<<<aggGrid, 256, 0, stream>>>(t, off, csr_src, b2, out, N);
}

// Round 5
// 284.568 us; speedup vs baseline: 3.5611x; 1.0842x over previous
//
#include <hip/hip_runtime.h>

#define NN 50000
#define EE 800000

typedef unsigned short u16;
typedef __attribute__((ext_vector_type(8))) short short8;   // 8 bf16 (4 VGPRs)
typedef __attribute__((ext_vector_type(4))) float f32x4;
typedef __attribute__((ext_vector_type(4))) unsigned short ushort4v;

__device__ __forceinline__ float b2f(u16 u) {
    return __uint_as_float(((unsigned)u) << 16);
}
__device__ __forceinline__ u16 f2b(float f) {
    unsigned u = __float_as_uint(f);
    return (u16)((u + 0x7FFF + ((u >> 16) & 1)) >> 16);   // RNE
}

// ---------------------------------------------------------------------------
// pack W0/W1/W2(padded) into MFMA B-fragment order (bf16):
// Wf[set][ (nt*4+kt)*64 + lane ][j] = W[k][n],
//   k = kt*32 + (lane>>4)*8 + j, n = nt*16 + (lane&15)
// grid: set*32 + nt*4 + kt  (96 blocks x 64 threads)
// ---------------------------------------------------------------------------
__global__ __launch_bounds__(64) void prep_w(
    const float* __restrict__ W0, const float* __restrict__ W1,
    const float* __restrict__ W2, u16* __restrict__ Wf)
{
    int b = blockIdx.x;
    int set = b >> 5, nt = (b >> 2) & 7, kt = b & 3;
    int lane = threadIdx.x;
    const float* W = (set == 0) ? W0 : (set == 1) ? W1 : W2;
    int ld = (set == 2) ? 40 : 128;
    int ncols = (set == 2) ? 40 : 128;
    int n = nt * 16 + (lane & 15);
    int kbase = kt * 32 + (lane >> 4) * 8;
    u16* dst = Wf + set * 16384 + (size_t)((nt * 4 + kt) * 64 + lane) * 8;
#pragma unroll
    for (int j = 0; j < 8; j++) {
        float v = (n < ncols) ? W[(kbase + j) * ld + n] : 0.f;
        dst[j] = f2b(v);
    }
}

// ---------------------------------------------------------------------------
// MFMA GEMM: out[n][m] = sum_k A[n][k] * W[k][m], K=128, bf16 MFMA.
// block = 4 waves, each wave computes a 16 x (NT*16) strip.
// A frag:  A[m=lane&15][k=(lane>>4)*8+j]   (contiguous 16B per lane)
// D frag:  col=lane&15, row=(lane>>4)*4+r  (m89-verified)
// F32IN: read fp32 A (stride 128), convert in-register.
// ---------------------------------------------------------------------------
template<int NT, int OSTRIDE, bool F32IN>
__global__ __launch_bounds__(256) void gemm_mfma_t(
    const void* __restrict__ Ap, const u16* __restrict__ Wf,
    u16* __restrict__ out, int N)
{
    const int wave = threadIdx.x >> 6;
    const int lane = threadIdx.x & 63;
    const int m = lane & 15;
    const int q = lane >> 4;
    const int rowBase = blockIdx.x * 64 + wave * 16;
    const int arow = rowBase + m;
    const bool rowOk = (arow < N);

    short8 af[4];
#pragma unroll
    for (int kt = 0; kt < 4; kt++) {
        if (rowOk) {
            if (F32IN) {
                const float* A = (const float*)Ap;
                float4 lo = *(const float4*)(A + (size_t)arow * 128 + kt * 32 + q * 8);
                float4 hi = *(const float4*)(A + (size_t)arow * 128 + kt * 32 + q * 8 + 4);
                short8 v;
                v[0] = (short)f2b(lo.x); v[1] = (short)f2b(lo.y);
                v[2] = (short)f2b(lo.z); v[3] = (short)f2b(lo.w);
                v[4] = (short)f2b(hi.x); v[5] = (short)f2b(hi.y);
                v[6] = (short)f2b(hi.z); v[7] = (short)f2b(hi.w);
                af[kt] = v;
            } else {
                const u16* A = (const u16*)Ap;
                af[kt] = *(const short8*)(A + (size_t)arow * 128 + kt * 32 + q * 8);
            }
        } else {
            af[kt] = (short8)0;
        }
    }

    f32x4 acc[NT];
#pragma unroll
    for (int nt = 0; nt < NT; nt++) acc[nt] = (f32x4)0.f;

#pragma unroll
    for (int kt = 0; kt < 4; kt++) {
#pragma unroll
        for (int nt = 0; nt < NT; nt++) {
            short8 bf = *(const short8*)(Wf + (size_t)((nt * 4 + kt) * 64 + lane) * 8);
            acc[nt] = __builtin_amdgcn_mfma_f32_16x16x32_bf16(af[kt], bf, acc[nt], 0, 0, 0);
        }
    }

#pragma unroll
    for (int nt = 0; nt < NT; nt++) {
#pragma unroll
        for (int r = 0; r < 4; r++) {
            int orow = rowBase + q * 4 + r;
            if (orow < N) out[(size_t)orow * OSTRIDE + nt * 16 + m] = f2b(acc[nt][r]);
        }
    }
}

// ---------------------------------------------------------------------------
// CSR build: histogram -> multi-block scan -> sliced fill
// ---------------------------------------------------------------------------
__global__ __launch_bounds__(256) void build_deg(
    const int* __restrict__ dst, int* __restrict__ deg, int E)
{
    int e = blockIdx.x * 256 + threadIdx.x;
    if (e < E) atomicAdd(&deg[dst[e]], 1);
}

__global__ __launch_bounds__(1024) void block_scan(
    const int* __restrict__ deg, int* __restrict__ off,
    int* __restrict__ blockSums, int N)
{
    __shared__ int sh[1024];
    const int t = threadIdx.x;
    const int idx = blockIdx.x * 1024 + t;
    const int v = (idx < N) ? deg[idx] : 0;
    sh[t] = v;
    __syncthreads();
    for (int d = 1; d < 1024; d <<= 1) {
        int u = (t >= d) ? sh[t - d] : 0;
        __syncthreads();
        sh[t] += u;
        __syncthreads();
    }
    if (idx < N) off[idx] = sh[t] - v;
    if (t == 1023) blockSums[blockIdx.x] = sh[t];
}

__global__ __launch_bounds__(64) void scan_sums(
    int* __restrict__ blockSums, int nb)
{
    const int t = threadIdx.x;
    const int orig = (t < nb) ? blockSums[t] : 0;
    int v = orig;
#pragma unroll
    for (int d = 1; d < 64; d <<= 1) {
        int u = __shfl_up(v, d);
        if (t >= d) v += u;
    }
    if (t < nb) blockSums[t] = v - orig;
}

__global__ __launch_bounds__(1024) void add_offsets(
    int* __restrict__ off, int* __restrict__ cursor,
    const int* __restrict__ blockSums, int N, int E)
{
    const int idx = blockIdx.x * 1024 + threadIdx.x;
    if (idx < N) {
        int o = off[idx] + blockSums[blockIdx.x];
        off[idx] = o;
        cursor[idx] = o;
    }
    if (idx == 0) off[N] = E;
}

// slice = dst>>13 (0..6). grid (eBlocks, 7), x-fastest dispatch => one slice's
// CSR region (~460 KB) is write-hot at a time -> dirty lines accumulate all
// their stores before eviction (fix for 16x write amplification).
__global__ __launch_bounds__(256) void fill_csr_sliced(
    const int* __restrict__ src, const int* __restrict__ dst,
    int* __restrict__ cursor, int* __restrict__ csr_src, int E)
{
    int e = blockIdx.x * 256 + threadIdx.x;
    if (e >= E) return;
    int d = dst[e];
    if ((d >> 13) != (int)blockIdx.y) return;
    int pos = atomicAdd(&cursor[d], 1);
    csr_src[pos] = src[e];
}

// ---------------------------------------------------------------------------
// aggregate 128 feats (bf16 rows, fp32 accum) + bias + relu -> bf16
// 16 lanes x 16B per node, 16 nodes per block, 4 outstanding gathers
// ---------------------------------------------------------------------------
__global__ __launch_bounds__(256) void agg128b(
    const u16* __restrict__ val, const int* __restrict__ off,
    const int* __restrict__ csr_src, const float* __restrict__ bias,
    u16* __restrict__ out, int N)
{
    const int c = threadIdx.x & 15;
    const int node = blockIdx.x * 16 + (threadIdx.x >> 4);
    if (node >= N) return;
    const int beg = off[node], end = off[node + 1];

    float a0[8] = {0, 0, 0, 0, 0, 0, 0, 0};
    float a1[8] = {0, 0, 0, 0, 0, 0, 0, 0};
    int i = beg;
    for (; i + 3 < end; i += 4) {
        int s0 = csr_src[i];
        int s1 = csr_src[i + 1];
        int s2 = csr_src[i + 2];
        int s3 = csr_src[i + 3];
        short8 v0 = *(const short8*)(val + (size_t)s0 * 128 + c * 8);
        short8 v1 = *(const short8*)(val + (size_t)s1 * 128 + c * 8);
        short8 v2 = *(const short8*)(val + (size_t)s2 * 128 + c * 8);
        short8 v3 = *(const short8*)(val + (size_t)s3 * 128 + c * 8);
#pragma unroll
        for (int j = 0; j < 8; j++) {
            a0[j] += b2f((u16)v0[j]) + b2f((u16)v2[j]);
            a1[j] += b2f((u16)v1[j]) + b2f((u16)v3[j]);
        }
    }
    for (; i < end; i++) {
        int s0 = csr_src[i];
        short8 v0 = *(const short8*)(val + (size_t)s0 * 128 + c * 8);
#pragma unroll
        for (int j = 0; j < 8; j++) a0[j] += b2f((u16)v0[j]);
    }

    float4 bA = *(const float4*)(bias + c * 8);
    float4 bB = *(const float4*)(bias + c * 8 + 4);
    float bb[8] = {bA.x, bA.y, bA.z, bA.w, bB.x, bB.y, bB.z, bB.w};
    short8 o;
#pragma unroll
    for (int j = 0; j < 8; j++)
        o[j] = (short)f2b(fmaxf(a0[j] + a1[j] + bb[j], 0.f));
    *(short8*)(out + (size_t)node * 128 + c * 8) = o;
}

// ---------------------------------------------------------------------------
// aggregate first 40 feats of bf16 stride-48 rows, + b2 -> fp32 d_out
// 16 lanes/node (10 active, ushort4 each), 16 nodes per block
// compact 48-col rows: 4.8 MB working set ~= per-XCD L2 resident
// ---------------------------------------------------------------------------
__global__ __launch_bounds__(256) void agg40b(
    const u16* __restrict__ val, const int* __restrict__ off,
    const int* __restrict__ csr_src, const float* __restrict__ b2,
    float* __restrict__ out, int N)
{
    const int c = threadIdx.x & 15;
    const int node = blockIdx.x * 16 + (threadIdx.x >> 4);
    if (node >= N || c >= 10) return;
    const int beg = off[node], end = off[node + 1];

    float a0[4] = {0, 0, 0, 0};
    float a1[4] = {0, 0, 0, 0};
    int i = beg;
    for (; i + 1 < end; i += 2) {
        int s0 = csr_src[i];
        int s1 = csr_src[i + 1];
        ushort4v v0 = *(const ushort4v*)(val + (size_t)s0 * 48 + c * 4);
        ushort4v v1 = *(const ushort4v*)(val + (size_t)s1 * 48 + c * 4);
        a0[0] += b2f(v0.x); a0[1] += b2f(v0.y); a0[2] += b2f(v0.z); a0[3] += b2f(v0.w);
        a1[0] += b2f(v1.x); a1[1] += b2f(v1.y); a1[2] += b2f(v1.z); a1[3] += b2f(v1.w);
    }
    if (i < end) {
        int s0 = csr_src[i];
        ushort4v v0 = *(const ushort4v*)(val + (size_t)s0 * 48 + c * 4);
        a0[0] += b2f(v0.x); a0[1] += b2f(v0.y); a0[2] += b2f(v0.z); a0[3] += b2f(v0.w);
    }
    float4 b = *(const float4*)(b2 + c * 4);
    float4 r;
    r.x = a0[0] + a1[0] + b.x;
    r.y = a0[1] + a1[1] + b.y;
    r.z = a0[2] + a1[2] + b.z;
    r.w = a0[3] + a1[3] + b.w;
    *(float4*)(out + (size_t)node * 40 + c * 4) = r;
}

extern "C" void kernel_launch(void* const* d_in, const int* in_sizes, int n_in,
                              void* d_out, int out_size, void* d_ws, size_t ws_size,
                              hipStream_t stream)
{
    const float* x  = (const float*)d_in[0];
    const int*   ei = (const int*)d_in[1];
    const float* W0 = (const float*)d_in[2];
    const float* b0 = (const float*)d_in[3];
    const float* W1 = (const float*)d_in[4];
    const float* b1 = (const float*)d_in[5];
    const float* W2 = (const float*)d_in[6];
    const float* b2 = (const float*)d_in[7];
    float* out = (float*)d_out;

    const int N = NN, E = EE;
    const int* src = ei;        // edge_index[0]
    const int* dst = ei + E;    // edge_index[1]

    char* ws = (char*)d_ws;
    u16* t       = (u16*)ws;                        // 12.8 MB (GEMM out)
    u16* hb      = (u16*)(ws + 12800000);           // 12.8 MB (agg out)
    u16* Wf      = (u16*)(ws + 25600000);           // 96 KB (3 frag-packed W)
    int* deg     = (int*)(ws + 25700000);           // 200 KB
    int* off     = (int*)(ws + 25900000);           // 200 KB (N+1)
    int* cursor  = (int*)(ws + 26100004);           // 200 KB
    int* csr_src = (int*)(ws + 26300004);           // 3.2 MB
    int* blkSums = (int*)(ws + 29500004);           // 196 B

    const int eGrid = (E + 255) / 256;              // 3125
    const int nScanBlocks = (N + 1023) / 1024;      // 49
    const int gemmGrid = (N + 63) / 64;             // 782
    const int aggGrid = (N + 15) / 16;              // 3125
    const int nSlices = ((N - 1) >> 13) + 1;        // 7

    // ---- CSR build (reused by all 3 layers)
    hipMemsetAsync(deg, 0, (size_t)N * 4, stream);
    build_deg<<<eGrid, 256, 0, stream>>>(dst, deg, E);
    block_scan<<<nScanBlocks, 1024, 0, stream>>>(deg, off, blkSums, N);
    scan_sums<<<1, 64, 0, stream>>>(blkSums, nScanBlocks);
    add_offsets<<<nScanBlocks, 1024, 0, stream>>>(off, cursor, blkSums, N, E);
    fill_csr_sliced<<<dim3(eGrid, nSlices), 256, 0, stream>>>(src, dst, cursor, csr_src, E);

    // ---- weight prep
    prep_w<<<96, 64, 0, stream>>>(W0, W1, W2, Wf);

    // ---- layer 0: t = bf16(x) @ W0 ; hb = relu(agg(t) + b0)
    gemm_mfma_t<8, 128, true><<<gemmGrid, 256, 0, stream>>>(x, Wf, t, N);
    agg128b<<<aggGrid, 256, 0, stream>>>(t, off, csr_src, b0, hb, N);

    // ---- layer 1: t = hb @ W1 ; hb = relu(agg(t) + b1)
    gemm_mfma_t<8, 128, false><<<gemmGrid, 256, 0, stream>>>(hb, Wf + 16384, t, N);
    agg128b<<<aggGrid, 256, 0, stream>>>(t, off, csr_src, b1, hb, N);

    // ---- layer 2: t48 = hb @ W2pad (48 cols, stride 48) ; out = agg40(t48) + b2
    gemm_mfma_t<3, 48, false><<<gemmGrid, 256, 0, stream>>>(hb, Wf + 32768, t, N);
    agg40b<<<aggGrid, 256, 0, stream>>>(t, off, csr_src, b2, out, N);
}

// Round 6
// 229.474 us; speedup vs baseline: 4.4161x; 1.2401x over previous
//
#include <hip/hip_runtime.h>

#define NN 50000
#define EE 800000

#define BKT 196      // buckets = dst>>8 (256 nodes each)
#define GB  334      // histogram/scatter blocks
#define EPB 2396     // edges per block (334*2396 = 800264 >= E)
#define CAP 5120     // LDS staging capacity per bucket (mean 4081, +16 sigma)

typedef unsigned short u16;
typedef __attribute__((ext_vector_type(8))) short short8;   // 8 bf16 (4 VGPRs)
typedef __attribute__((ext_vector_type(4))) float f32x4;
typedef __attribute__((ext_vector_type(4))) unsigned short ushort4v;

__device__ __forceinline__ float b2f(u16 u) {
    return __uint_as_float(((unsigned)u) << 16);
}
__device__ __forceinline__ u16 f2b(float f) {
    unsigned u = __float_as_uint(f);
    return (u16)((u + 0x7FFF + ((u >> 16) & 1)) >> 16);   // RNE
}

// ---------------------------------------------------------------------------
// pack W0/W1/W2(padded) into MFMA B-fragment order (bf16)
// ---------------------------------------------------------------------------
__global__ __launch_bounds__(64) void prep_w(
    const float* __restrict__ W0, const float* __restrict__ W1,
    const float* __restrict__ W2, u16* __restrict__ Wf)
{
    int b = blockIdx.x;
    int set = b >> 5, nt = (b >> 2) & 7, kt = b & 3;
    int lane = threadIdx.x;
    const float* W = (set == 0) ? W0 : (set == 1) ? W1 : W2;
    int ld = (set == 2) ? 40 : 128;
    int ncols = (set == 2) ? 40 : 128;
    int n = nt * 16 + (lane & 15);
    int kbase = kt * 32 + (lane >> 4) * 8;
    u16* dst = Wf + set * 16384 + (size_t)((nt * 4 + kt) * 64 + lane) * 8;
#pragma unroll
    for (int j = 0; j < 8; j++) {
        float v = (n < ncols) ? W[(kbase + j) * ld + n] : 0.f;
        dst[j] = f2b(v);
    }
}

// ---------------------------------------------------------------------------
// MFMA GEMM: out[n][m] = sum_k A[n][k] * W[k][m], K=128, bf16 MFMA.
// ---------------------------------------------------------------------------
template<int NT, int OSTRIDE, bool F32IN>
__global__ __launch_bounds__(256) void gemm_mfma_t(
    const void* __restrict__ Ap, const u16* __restrict__ Wf,
    u16* __restrict__ out, int N)
{
    const int wave = threadIdx.x >> 6;
    const int lane = threadIdx.x & 63;
    const int m = lane & 15;
    const int q = lane >> 4;
    const int rowBase = blockIdx.x * 64 + wave * 16;
    const int arow = rowBase + m;
    const bool rowOk = (arow < N);

    short8 af[4];
#pragma unroll
    for (int kt = 0; kt < 4; kt++) {
        if (rowOk) {
            if (F32IN) {
                const float* A = (const float*)Ap;
                float4 lo = *(const float4*)(A + (size_t)arow * 128 + kt * 32 + q * 8);
                float4 hi = *(const float4*)(A + (size_t)arow * 128 + kt * 32 + q * 8 + 4);
                short8 v;
                v[0] = (short)f2b(lo.x); v[1] = (short)f2b(lo.y);
                v[2] = (short)f2b(lo.z); v[3] = (short)f2b(lo.w);
                v[4] = (short)f2b(hi.x); v[5] = (short)f2b(hi.y);
                v[6] = (short)f2b(hi.z); v[7] = (short)f2b(hi.w);
                af[kt] = v;
            } else {
                const u16* A = (const u16*)Ap;
                af[kt] = *(const short8*)(A + (size_t)arow * 128 + kt * 32 + q * 8);
            }
        } else {
            af[kt] = (short8)0;
        }
    }

    f32x4 acc[NT];
#pragma unroll
    for (int nt = 0; nt < NT; nt++) acc[nt] = (f32x4)0.f;

#pragma unroll
    for (int kt = 0; kt < 4; kt++) {
#pragma unroll
        for (int nt = 0; nt < NT; nt++) {
            short8 bf = *(const short8*)(Wf + (size_t)((nt * 4 + kt) * 64 + lane) * 8);
            acc[nt] = __builtin_amdgcn_mfma_f32_16x16x32_bf16(af[kt], bf, acc[nt], 0, 0, 0);
        }
    }

#pragma unroll
    for (int nt = 0; nt < NT; nt++) {
#pragma unroll
        for (int r = 0; r < 4; r++) {
            int orow = rowBase + q * 4 + r;
            if (orow < N) out[(size_t)orow * OSTRIDE + nt * 16 + m] = f2b(acc[nt][r]);
        }
    }
}

// ---------------------------------------------------------------------------
// CSR build, pass 1: per-block LDS histogram over 196 buckets (dst>>8)
// BBC[bucket][block] = count
// ---------------------------------------------------------------------------
__global__ __launch_bounds__(256) void hist_buckets(
    const int* __restrict__ dst, int* __restrict__ BBC, int E)
{
    __shared__ int cnt[BKT];
    const int g = blockIdx.x, t = threadIdx.x;
    for (int b = t; b < BKT; b += 256) cnt[b] = 0;
    __syncthreads();
    const int beg = g * EPB, end = min(E, beg + EPB);
    for (int e = beg + t; e < end; e += 256)
        atomicAdd(&cnt[dst[e] >> 8], 1);
    __syncthreads();
    for (int b = t; b < BKT; b += 256) BBC[b * GB + g] = cnt[b];
}

// generic multi-block exclusive scan, phase 1 (local excl + block totals)
__global__ __launch_bounds__(1024) void block_scan(
    const int* __restrict__ in, int* __restrict__ out,
    int* __restrict__ blockSums, int M)
{
    __shared__ int sh[1024];
    const int t = threadIdx.x;
    const int idx = blockIdx.x * 1024 + t;
    const int v = (idx < M) ? in[idx] : 0;
    sh[t] = v;
    __syncthreads();
    for (int d = 1; d < 1024; d <<= 1) {
        int u = (t >= d) ? sh[t - d] : 0;
        __syncthreads();
        sh[t] += u;
        __syncthreads();
    }
    if (idx < M) out[idx] = sh[t] - v;
    if (t == 1023) blockSums[blockIdx.x] = sh[t];
}

__global__ __launch_bounds__(64) void scan_sums(
    int* __restrict__ blockSums, int nb)
{
    const int t = threadIdx.x;
    const int orig = (t < nb) ? blockSums[t] : 0;
    int v = orig;
#pragma unroll
    for (int d = 1; d < 64; d <<= 1) {
        int u = __shfl_up(v, d);
        if (t >= d) v += u;
    }
    if (t < nb) blockSums[t] = v - orig;
}

__global__ __launch_bounds__(1024) void add_base(
    int* __restrict__ S, const int* __restrict__ blockSums, int M)
{
    const int idx = blockIdx.x * 1024 + threadIdx.x;
    if (idx < M) S[idx] += blockSums[blockIdx.x];
}

// ---------------------------------------------------------------------------
// CSR build, pass 2: scatter (src,dst) pairs into per-(bucket,block) segments.
// LDS cursors -> each block's writes land in its own contiguous runs.
// ---------------------------------------------------------------------------
__global__ __launch_bounds__(256) void scatter_pairs(
    const int* __restrict__ src, const int* __restrict__ dst,
    const int* __restrict__ S, int2* __restrict__ pairs, int E)
{
    __shared__ int cur[BKT];
    const int g = blockIdx.x, t = threadIdx.x;
    for (int b = t; b < BKT; b += 256) cur[b] = S[b * GB + g];
    __syncthreads();
    const int beg = g * EPB, end = min(E, beg + EPB);
    for (int e = beg + t; e < end; e += 256) {
        int d = dst[e];
        int pos = atomicAdd(&cur[d >> 8], 1);
        pairs[pos] = make_int2(src[e], d);
    }
}

// ---------------------------------------------------------------------------
// CSR build, pass 3: per-bucket node sort, fully LDS-staged.
// One block per bucket (~4096 edges, 256 nodes). Produces off[] and csr_src[]
// with only coalesced global writes.
// ---------------------------------------------------------------------------
__global__ __launch_bounds__(256) void bucket_sort(
    const int2* __restrict__ pairs, const int* __restrict__ S,
    int* __restrict__ off, int* __restrict__ csr, int N, int E)
{
    __shared__ int sdeg[256];
    __shared__ int sex[256];
    __shared__ int scur[256];
    __shared__ int stage[CAP];
    const int b = blockIdx.x, t = threadIdx.x;
    const int base = S[b * GB];
    const int end  = (b == BKT - 1) ? E : S[(b + 1) * GB];
    const int cnt = end - base;

    sdeg[t] = 0;
    __syncthreads();
    for (int i = t; i < cnt; i += 256)
        atomicAdd(&sdeg[pairs[base + i].y & 255], 1);
    __syncthreads();

    int v = sdeg[t];
    sex[t] = v;
    __syncthreads();
    for (int d = 1; d < 256; d <<= 1) {
        int u = (t >= d) ? sex[t - d] : 0;
        __syncthreads();
        sex[t] += u;
        __syncthreads();
    }
    const int excl = sex[t] - v;
    const int node = b * 256 + t;
    if (node < N) off[node] = base + excl;
    if (b == BKT - 1 && t == 0) off[N] = E;
    scur[t] = excl;
    __syncthreads();

    if (cnt <= CAP) {
        for (int i = t; i < cnt; i += 256) {
            int2 p = pairs[base + i];
            int pos = atomicAdd(&scur[p.y & 255], 1);
            stage[pos] = p.x;
        }
        __syncthreads();
        for (int i = t; i < cnt; i += 256) csr[base + i] = stage[i];
    } else {
        // overflow fallback (not expected for this graph)
        for (int i = t; i < cnt; i += 256) {
            int2 p = pairs[base + i];
            int pos = atomicAdd(&scur[p.y & 255], 1);
            csr[base + pos] = p.x;
        }
    }
}

// ---------------------------------------------------------------------------
// aggregate 128 feats (bf16 rows, fp32 accum) + bias + relu -> bf16
// ---------------------------------------------------------------------------
__global__ __launch_bounds__(256) void agg128b(
    const u16* __restrict__ val, const int* __restrict__ off,
    const int* __restrict__ csr_src, const float* __restrict__ bias,
    u16* __restrict__ out, int N)
{
    const int c = threadIdx.x & 15;
    const int node = blockIdx.x * 16 + (threadIdx.x >> 4);
    if (node >= N) return;
    const int beg = off[node], end = off[node + 1];

    float a0[8] = {0, 0, 0, 0, 0, 0, 0, 0};
    float a1[8] = {0, 0, 0, 0, 0, 0, 0, 0};
    int i = beg;
    for (; i + 3 < end; i += 4) {
        int s0 = csr_src[i];
        int s1 = csr_src[i + 1];
        int s2 = csr_src[i + 2];
        int s3 = csr_src[i + 3];
        short8 v0 = *(const short8*)(val + (size_t)s0 * 128 + c * 8);
        short8 v1 = *(const short8*)(val + (size_t)s1 * 128 + c * 8);
        short8 v2 = *(const short8*)(val + (size_t)s2 * 128 + c * 8);
        short8 v3 = *(const short8*)(val + (size_t)s3 * 128 + c * 8);
#pragma unroll
        for (int j = 0; j < 8; j++) {
            a0[j] += b2f((u16)v0[j]) + b2f((u16)v2[j]);
            a1[j] += b2f((u16)v1[j]) + b2f((u16)v3[j]);
        }
    }
    for (; i < end; i++) {
        int s0 = csr_src[i];
        short8 v0 = *(const short8*)(val + (size_t)s0 * 128 + c * 8);
#pragma unroll
        for (int j = 0; j < 8; j++) a0[j] += b2f((u16)v0[j]);
    }

    float4 bA = *(const float4*)(bias + c * 8);
    float4 bB = *(const float4*)(bias + c * 8 + 4);
    float bb[8] = {bA.x, bA.y, bA.z, bA.w, bB.x, bB.y, bB.z, bB.w};
    short8 o;
#pragma unroll
    for (int j = 0; j < 8; j++)
        o[j] = (short)f2b(fmaxf(a0[j] + a1[j] + bb[j], 0.f));
    *(short8*)(out + (size_t)node * 128 + c * 8) = o;
}

// ---------------------------------------------------------------------------
// aggregate first 40 feats of bf16 stride-48 rows, + b2 -> fp32 d_out
// ---------------------------------------------------------------------------
__global__ __launch_bounds__(256) void agg40b(
    const u16* __restrict__ val, const int* __restrict__ off,
    const int* __restrict__ csr_src, const float* __restrict__ b2,
    float* __restrict__ out, int N)
{
    const int c = threadIdx.x & 15;
    const int node = blockIdx.x * 16 + (threadIdx.x >> 4);
    if (node >= N || c >= 10) return;
    const int beg = off[node], end = off[node + 1];

    float a0[4] = {0, 0, 0, 0};
    float a1[4] = {0, 0, 0, 0};
    int i = beg;
    for (; i + 1 < end; i += 2) {
        int s0 = csr_src[i];
        int s1 = csr_src[i + 1];
        ushort4v v0 = *(const ushort4v*)(val + (size_t)s0 * 48 + c * 4);
        ushort4v v1 = *(const ushort4v*)(val + (size_t)s1 * 48 + c * 4);
        a0[0] += b2f(v0.x); a0[1] += b2f(v0.y); a0[2] += b2f(v0.z); a0[3] += b2f(v0.w);
        a1[0] += b2f(v1.x); a1[1] += b2f(v1.y); a1[2] += b2f(v1.z); a1[3] += b2f(v1.w);
    }
    if (i < end) {
        int s0 = csr_src[i];
        ushort4v v0 = *(const ushort4v*)(val + (size_t)s0 * 48 + c * 4);
        a0[0] += b2f(v0.x); a0[1] += b2f(v0.y); a0[2] += b2f(v0.z); a0[3] += b2f(v0.w);
    }
    float4 b = *(const float4*)(b2 + c * 4);
    float4 r;
    r.x = a0[0] + a1[0] + b.x;
    r.y = a0[1] + a1[1] + b.y;
    r.z = a0[2] + a1[2] + b.z;
    r.w = a0[3] + a1[3] + b.w;
    *(float4*)(out + (size_t)node * 40 + c * 4) = r;
}

extern "C" void kernel_launch(void* const* d_in, const int* in_sizes, int n_in,
                              void* d_out, int out_size, void* d_ws, size_t ws_size,
                              hipStream_t stream)
{
    const float* x  = (const float*)d_in[0];
    const int*   ei = (const int*)d_in[1];
    const float* W0 = (const float*)d_in[2];
    const float* b0 = (const float*)d_in[3];
    const float* W1 = (const float*)d_in[4];
    const float* b1 = (const float*)d_in[5];
    const float* W2 = (const float*)d_in[6];
    const float* b2 = (const float*)d_in[7];
    float* out = (float*)d_out;

    const int N = NN, E = EE;
    const int* src = ei;        // edge_index[0]
    const int* dst = ei + E;    // edge_index[1]

    char* ws = (char*)d_ws;
    u16*  t       = (u16*) ws;                      // 12.8 MB (GEMM out)
    u16*  hb      = (u16*) (ws + 12800000);         // 12.8 MB (agg out)
    u16*  Wf      = (u16*) (ws + 25600000);         // 96 KB (frag-packed W)
    int*  off     = (int*) (ws + 25700000);         // 200 KB (N+1)
    int*  csr_src = (int*) (ws + 25900008);         // 3.2 MB
    int*  BBC     = (int*) (ws + 29100008);         // 262 KB (raw counts)
    int*  S       = (int*) (ws + 29361864);         // 262 KB (scanned)
    int*  blkSums = (int*) (ws + 29623720);         // 256 B
    int2* pairs   = (int2*)(ws + 29623976);         // 6.4 MB (8B aligned)

    const int M = BKT * GB;                         // 65464
    const int nScan = (M + 1023) / 1024;            // 64
    const int gemmGrid = (N + 63) / 64;             // 782
    const int aggGrid = (N + 15) / 16;              // 3125

    // ---- CSR build: LDS-staged bucketed counting sort
    hist_buckets<<<GB, 256, 0, stream>>>(dst, BBC, E);
    block_scan<<<nScan, 1024, 0, stream>>>(BBC, S, blkSums, M);
    scan_sums<<<1, 64, 0, stream>>>(blkSums, nScan);
    add_base<<<nScan, 1024, 0, stream>>>(S, blkSums, M);
    scatter_pairs<<<GB, 256, 0, stream>>>(src, dst, S, pairs, E);
    bucket_sort<<<BKT, 256, 0, stream>>>(pairs, S, off, csr_src, N, E);

    // ---- weight prep
    prep_w<<<96, 64, 0, stream>>>(W0, W1, W2, Wf);

    // ---- layer 0: t = bf16(x) @ W0 ; hb = relu(agg(t) + b0)
    gemm_mfma_t<8, 128, true><<<gemmGrid, 256, 0, stream>>>(x, Wf, t, N);
    agg128b<<<aggGrid, 256, 0, stream>>>(t, off, csr_src, b0, hb, N);

    // ---- layer 1: t = hb @ W1 ; hb = relu(agg(t) + b1)
    gemm_mfma_t<8, 128, false><<<gemmGrid, 256, 0, stream>>>(hb, Wf + 16384, t, N);
    agg128b<<<aggGrid, 256, 0, stream>>>(t, off, csr_src, b1, hb, N);

    // ---- layer 2: t48 = hb @ W2pad (48 cols) ; out = agg40(t48) + b2
    gemm_mfma_t<3, 48, false><<<gemmGrid, 256, 0, stream>>>(hb, Wf + 32768, t, N);
    agg40b<<<aggGrid, 256, 0, stream>>>(t, off, csr_src, b2, out, N);
}

// Round 7
// 224.366 us; speedup vs baseline: 4.5166x; 1.0228x over previous
//
#include <hip/hip_runtime.h>

#define NN 50000
#define EE 800000

#define BKT 196      // buckets = dst>>8 (256 nodes each)
#define GB  334      // histogram/scatter blocks
#define EPB 2396     // edges per block (334*2396 = 800264 >= E)
#define CAP 5120     // LDS staging capacity per bucket (mean 4081, +16 sigma)

typedef unsigned short u16;
typedef __attribute__((ext_vector_type(8))) short short8;   // 8 bf16 (4 VGPRs)
typedef __attribute__((ext_vector_type(4))) float f32x4;
typedef __attribute__((ext_vector_type(4))) unsigned short ushort4v;

__device__ __forceinline__ float b2f(u16 u) {
    return __uint_as_float(((unsigned)u) << 16);
}
__device__ __forceinline__ u16 f2b(float f) {
    unsigned u = __float_as_uint(f);
    return (u16)((u + 0x7FFF + ((u >> 16) & 1)) >> 16);   // RNE
}

// ---------------------------------------------------------------------------
// pack W0/W1/W2(padded) into MFMA B-fragment order (bf16)
// ---------------------------------------------------------------------------
__global__ __launch_bounds__(64) void prep_w(
    const float* __restrict__ W0, const float* __restrict__ W1,
    const float* __restrict__ W2, u16* __restrict__ Wf)
{
    int b = blockIdx.x;
    int set = b >> 5, nt = (b >> 2) & 7, kt = b & 3;
    int lane = threadIdx.x;
    const float* W = (set == 0) ? W0 : (set == 1) ? W1 : W2;
    int ld = (set == 2) ? 40 : 128;
    int ncols = (set == 2) ? 40 : 128;
    int n = nt * 16 + (lane & 15);
    int kbase = kt * 32 + (lane >> 4) * 8;
    u16* dst = Wf + set * 16384 + (size_t)((nt * 4 + kt) * 64 + lane) * 8;
#pragma unroll
    for (int j = 0; j < 8; j++) {
        float v = (n < ncols) ? W[(kbase + j) * ld + n] : 0.f;
        dst[j] = f2b(v);
    }
}

// ---------------------------------------------------------------------------
// layer-0 GEMM: t[n][m] = sum_k bf16(x[n][k]) * W0[k][m]   (fp32 input)
// ---------------------------------------------------------------------------
__global__ __launch_bounds__(256) void gemm0(
    const float* __restrict__ A, const u16* __restrict__ Wf,
    u16* __restrict__ out, int N)
{
    const int wave = threadIdx.x >> 6;
    const int lane = threadIdx.x & 63;
    const int m = lane & 15;
    const int q = lane >> 4;
    const int rowBase = blockIdx.x * 64 + wave * 16;
    const int arow = rowBase + m;
    const bool rowOk = (arow < N);

    short8 af[4];
#pragma unroll
    for (int kt = 0; kt < 4; kt++) {
        if (rowOk) {
            float4 lo = *(const float4*)(A + (size_t)arow * 128 + kt * 32 + q * 8);
            float4 hi = *(const float4*)(A + (size_t)arow * 128 + kt * 32 + q * 8 + 4);
            short8 v;
            v[0] = (short)f2b(lo.x); v[1] = (short)f2b(lo.y);
            v[2] = (short)f2b(lo.z); v[3] = (short)f2b(lo.w);
            v[4] = (short)f2b(hi.x); v[5] = (short)f2b(hi.y);
            v[6] = (short)f2b(hi.z); v[7] = (short)f2b(hi.w);
            af[kt] = v;
        } else {
            af[kt] = (short8)0;
        }
    }

    f32x4 acc[8];
#pragma unroll
    for (int nt = 0; nt < 8; nt++) acc[nt] = (f32x4)0.f;

#pragma unroll
    for (int kt = 0; kt < 4; kt++) {
#pragma unroll
        for (int nt = 0; nt < 8; nt++) {
            short8 bf = *(const short8*)(Wf + (size_t)((nt * 4 + kt) * 64 + lane) * 8);
            acc[nt] = __builtin_amdgcn_mfma_f32_16x16x32_bf16(af[kt], bf, acc[nt], 0, 0, 0);
        }
    }

#pragma unroll
    for (int nt = 0; nt < 8; nt++) {
#pragma unroll
        for (int r = 0; r < 4; r++) {
            int orow = rowBase + q * 4 + r;
            if (orow < N) out[(size_t)orow * 128 + nt * 16 + m] = f2b(acc[nt][r]);
        }
    }
}

// ---------------------------------------------------------------------------
// FUSED layer: out = ( relu(agg(val) + bias) ) @ W
// block = 64 dst nodes, 512 threads (8 waves).
// phase 1: gather-aggregate 64 rows -> LDS (bf16, row stride 136)
// phase 2: MFMA from LDS; wave = (rowGroup 0..3) x (colHalf 0..1)
// ---------------------------------------------------------------------------
template<int NT, int OSTRIDE>
__global__ __launch_bounds__(512) void agg_gemm_t(
    const u16* __restrict__ val, const int* __restrict__ off,
    const int* __restrict__ csr, const float* __restrict__ bias,
    const u16* __restrict__ Wf, u16* __restrict__ out, int N)
{
    __shared__ u16 A[64][136];   // 17.4 KB, +8 pad breaks phase-2 bank aliasing
    const int tid = threadIdx.x;
    const int rowBase = blockIdx.x * 64;

    // ---- phase 1: aggregate, bias+relu, bf16 -> LDS
    {
        const int c = tid & 15;          // 16B chunk (8 bf16)
        const int nl = tid >> 4;         // 0..31
        float4 bA = *(const float4*)(bias + c * 8);
        float4 bB = *(const float4*)(bias + c * 8 + 4);
        float bb[8] = {bA.x, bA.y, bA.z, bA.w, bB.x, bB.y, bB.z, bB.w};
#pragma unroll
        for (int g = 0; g < 2; g++) {
            const int lrow = g * 32 + nl;
            const int node = rowBase + lrow;
            float a0[8] = {0, 0, 0, 0, 0, 0, 0, 0};
            float a1[8] = {0, 0, 0, 0, 0, 0, 0, 0};
            if (node < N) {
                const int beg = off[node], end = off[node + 1];
                int i = beg;
                for (; i + 3 < end; i += 4) {
                    int s0 = csr[i];
                    int s1 = csr[i + 1];
                    int s2 = csr[i + 2];
                    int s3 = csr[i + 3];
                    short8 v0 = *(const short8*)(val + (size_t)s0 * 128 + c * 8);
                    short8 v1 = *(const short8*)(val + (size_t)s1 * 128 + c * 8);
                    short8 v2 = *(const short8*)(val + (size_t)s2 * 128 + c * 8);
                    short8 v3 = *(const short8*)(val + (size_t)s3 * 128 + c * 8);
#pragma unroll
                    for (int j = 0; j < 8; j++) {
                        a0[j] += b2f((u16)v0[j]) + b2f((u16)v2[j]);
                        a1[j] += b2f((u16)v1[j]) + b2f((u16)v3[j]);
                    }
                }
                for (; i < end; i++) {
                    int s0 = csr[i];
                    short8 v0 = *(const short8*)(val + (size_t)s0 * 128 + c * 8);
#pragma unroll
                    for (int j = 0; j < 8; j++) a0[j] += b2f((u16)v0[j]);
                }
            }
            short8 o;
#pragma unroll
            for (int j = 0; j < 8; j++)
                o[j] = (short)f2b(fmaxf(a0[j] + a1[j] + bb[j], 0.f));
            *(short8*)&A[lrow][c * 8] = o;
        }
    }
    __syncthreads();

    // ---- phase 2: MFMA from LDS
    const int wave = tid >> 6;           // 0..7
    const int lane = tid & 63;
    const int m = lane & 15;
    const int q = lane >> 4;
    const int rg = wave & 3;             // row group (16 rows)
    const int ch = wave >> 2;            // col half
    const int lrow = rg * 16 + m;

    short8 af[4];
#pragma unroll
    for (int kt = 0; kt < 4; kt++)
        af[kt] = *(const short8*)&A[lrow][kt * 32 + q * 8];

    constexpr int NTH = (NT + 1) / 2;
    const int ntB = ch ? NTH : 0;
    const int ntE = ch ? NT : NTH;

    f32x4 acc[NTH];
#pragma unroll
    for (int i = 0; i < NTH; i++) acc[i] = (f32x4)0.f;

#pragma unroll
    for (int kt = 0; kt < 4; kt++) {
        for (int nt = ntB; nt < ntE; nt++) {
            short8 bf = *(const short8*)(Wf + (size_t)((nt * 4 + kt) * 64 + lane) * 8);
            acc[nt - ntB] = __builtin_amdgcn_mfma_f32_16x16x32_bf16(af[kt], bf, acc[nt - ntB], 0, 0, 0);
        }
    }

    for (int nt = ntB; nt < ntE; nt++) {
#pragma unroll
        for (int r = 0; r < 4; r++) {
            int orow = rowBase + rg * 16 + q * 4 + r;
            if (orow < N) out[(size_t)orow * OSTRIDE + nt * 16 + m] = f2b(acc[nt - ntB][r]);
        }
    }
}

// ---------------------------------------------------------------------------
// CSR build, pass 1: per-block LDS histogram over 196 buckets (dst>>8)
// ---------------------------------------------------------------------------
__global__ __launch_bounds__(256) void hist_buckets(
    const int* __restrict__ dst, int* __restrict__ BBC, int E)
{
    __shared__ int cnt[BKT];
    const int g = blockIdx.x, t = threadIdx.x;
    for (int b = t; b < BKT; b += 256) cnt[b] = 0;
    __syncthreads();
    const int beg = g * EPB, end = min(E, beg + EPB);
    for (int e = beg + t; e < end; e += 256)
        atomicAdd(&cnt[dst[e] >> 8], 1);
    __syncthreads();
    for (int b = t; b < BKT; b += 256) BBC[b * GB + g] = cnt[b];
}

__global__ __launch_bounds__(1024) void block_scan(
    const int* __restrict__ in, int* __restrict__ out,
    int* __restrict__ blockSums, int M)
{
    __shared__ int sh[1024];
    const int t = threadIdx.x;
    const int idx = blockIdx.x * 1024 + t;
    const int v = (idx < M) ? in[idx] : 0;
    sh[t] = v;
    __syncthreads();
    for (int d = 1; d < 1024; d <<= 1) {
        int u = (t >= d) ? sh[t - d] : 0;
        __syncthreads();
        sh[t] += u;
        __syncthreads();
    }
    if (idx < M) out[idx] = sh[t] - v;
    if (t == 1023) blockSums[blockIdx.x] = sh[t];
}

__global__ __launch_bounds__(64) void scan_sums(
    int* __restrict__ blockSums, int nb)
{
    const int t = threadIdx.x;
    const int orig = (t < nb) ? blockSums[t] : 0;
    int v = orig;
#pragma unroll
    for (int d = 1; d < 64; d <<= 1) {
        int u = __shfl_up(v, d);
        if (t >= d) v += u;
    }
    if (t < nb) blockSums[t] = v - orig;
}

__global__ __launch_bounds__(1024) void add_base(
    int* __restrict__ S, const int* __restrict__ blockSums, int M)
{
    const int idx = blockIdx.x * 1024 + threadIdx.x;
    if (idx < M) S[idx] += blockSums[blockIdx.x];
}

// ---------------------------------------------------------------------------
// CSR build, pass 2: scatter (src,dst) pairs into per-(bucket,block) segments
// ---------------------------------------------------------------------------
__global__ __launch_bounds__(256) void scatter_pairs(
    const int* __restrict__ src, const int* __restrict__ dst,
    const int* __restrict__ S, int2* __restrict__ pairs, int E)
{
    __shared__ int cur[BKT];
    const int g = blockIdx.x, t = threadIdx.x;
    for (int b = t; b < BKT; b += 256) cur[b] = S[b * GB + g];
    __syncthreads();
    const int beg = g * EPB, end = min(E, beg + EPB);
    for (int e = beg + t; e < end; e += 256) {
        int d = dst[e];
        int pos = atomicAdd(&cur[d >> 8], 1);
        pairs[pos] = make_int2(src[e], d);
    }
}

// ---------------------------------------------------------------------------
// CSR build, pass 3: per-bucket node sort, fully LDS-staged
// ---------------------------------------------------------------------------
__global__ __launch_bounds__(256) void bucket_sort(
    const int2* __restrict__ pairs, const int* __restrict__ S,
    int* __restrict__ off, int* __restrict__ csr, int N, int E)
{
    __shared__ int sdeg[256];
    __shared__ int sex[256];
    __shared__ int scur[256];
    __shared__ int stage[CAP];
    const int b = blockIdx.x, t = threadIdx.x;
    const int base = S[b * GB];
    const int end  = (b == BKT - 1) ? E : S[(b + 1) * GB];
    const int cnt = end - base;

    sdeg[t] = 0;
    __syncthreads();
    for (int i = t; i < cnt; i += 256)
        atomicAdd(&sdeg[pairs[base + i].y & 255], 1);
    __syncthreads();

    int v = sdeg[t];
    sex[t] = v;
    __syncthreads();
    for (int d = 1; d < 256; d <<= 1) {
        int u = (t >= d) ? sex[t - d] : 0;
        __syncthreads();
        sex[t] += u;
        __syncthreads();
    }
    const int excl = sex[t] - v;
    const int node = b * 256 + t;
    if (node < N) off[node] = base + excl;
    if (b == BKT - 1 && t == 0) off[N] = E;
    scur[t] = excl;
    __syncthreads();

    if (cnt <= CAP) {
        for (int i = t; i < cnt; i += 256) {
            int2 p = pairs[base + i];
            int pos = atomicAdd(&scur[p.y & 255], 1);
            stage[pos] = p.x;
        }
        __syncthreads();
        for (int i = t; i < cnt; i += 256) csr[base + i] = stage[i];
    } else {
        for (int i = t; i < cnt; i += 256) {
            int2 p = pairs[base + i];
            int pos = atomicAdd(&scur[p.y & 255], 1);
            csr[base + pos] = p.x;
        }
    }
}

// ---------------------------------------------------------------------------
// aggregate first 40 feats of bf16 stride-48 rows, + b2 -> fp32 d_out
// ---------------------------------------------------------------------------
__global__ __launch_bounds__(256) void agg40b(
    const u16* __restrict__ val, const int* __restrict__ off,
    const int* __restrict__ csr_src, const float* __restrict__ b2,
    float* __restrict__ out, int N)
{
    const int c = threadIdx.x & 15;
    const int node = blockIdx.x * 16 + (threadIdx.x >> 4);
    if (node >= N || c >= 10) return;
    const int beg = off[node], end = off[node + 1];

    float a0[4] = {0, 0, 0, 0};
    float a1[4] = {0, 0, 0, 0};
    int i = beg;
    for (; i + 1 < end; i += 2) {
        int s0 = csr_src[i];
        int s1 = csr_src[i + 1];
        ushort4v v0 = *(const ushort4v*)(val + (size_t)s0 * 48 + c * 4);
        ushort4v v1 = *(const ushort4v*)(val + (size_t)s1 * 48 + c * 4);
        a0[0] += b2f(v0.x); a0[1] += b2f(v0.y); a0[2] += b2f(v0.z); a0[3] += b2f(v0.w);
        a1[0] += b2f(v1.x); a1[1] += b2f(v1.y); a1[2] += b2f(v1.z); a1[3] += b2f(v1.w);
    }
    if (i < end) {
        int s0 = csr_src[i];
        ushort4v v0 = *(const ushort4v*)(val + (size_t)s0 * 48 + c * 4);
        a0[0] += b2f(v0.x); a0[1] += b2f(v0.y); a0[2] += b2f(v0.z); a0[3] += b2f(v0.w);
    }
    float4 b = *(const float4*)(b2 + c * 4);
    float4 r;
    r.x = a0[0] + a1[0] + b.x;
    r.y = a0[1] + a1[1] + b.y;
    r.z = a0[2] + a1[2] + b.z;
    r.w = a0[3] + a1[3] + b.w;
    *(float4*)(out + (size_t)node * 40 + c * 4) = r;
}

extern "C" void kernel_launch(void* const* d_in, const int* in_sizes, int n_in,
                              void* d_out, int out_size, void* d_ws, size_t ws_size,
                              hipStream_t stream)
{
    const float* x  = (const float*)d_in[0];
    const int*   ei = (const int*)d_in[1];
    const float* W0 = (const float*)d_in[2];
    const float* b0 = (const float*)d_in[3];
    const float* W1 = (const float*)d_in[4];
    const float* b1 = (const float*)d_in[5];
    const float* W2 = (const float*)d_in[6];
    const float* b2 = (const float*)d_in[7];
    float* out = (float*)d_out;

    const int N = NN, E = EE;
    const int* src = ei;        // edge_index[0]
    const int* dst = ei + E;    // edge_index[1]

    char* ws = (char*)d_ws;
    u16*  t       = (u16*) ws;                      // 12.8 MB (GEMM out, stride 128)
    u16*  t2      = (u16*) (ws + 12800000);         // 4.8 MB (layer-2 out, stride 48)
    u16*  Wf      = (u16*) (ws + 17600000);         // 96 KB (frag-packed W)
    int*  off     = (int*) (ws + 17700000);         // 200 KB (N+1)
    int*  csr_src = (int*) (ws + 17900008);         // 3.2 MB
    int*  BBC     = (int*) (ws + 21100008);         // 262 KB (raw counts)
    int*  S       = (int*) (ws + 21361864);         // 262 KB (scanned)
    int*  blkSums = (int*) (ws + 21623720);         // 256 B
    int2* pairs   = (int2*)(ws + 21623976);         // 6.4 MB (8B aligned)

    const int M = BKT * GB;                         // 65464
    const int nScan = (M + 1023) / 1024;            // 64
    const int tileGrid = (N + 63) / 64;             // 782
    const int aggGrid = (N + 15) / 16;              // 3125

    // ---- CSR build: LDS-staged bucketed counting sort
    hist_buckets<<<GB, 256, 0, stream>>>(dst, BBC, E);
    block_scan<<<nScan, 1024, 0, stream>>>(BBC, S, blkSums, M);
    scan_sums<<<1, 64, 0, stream>>>(blkSums, nScan);
    add_base<<<nScan, 1024, 0, stream>>>(S, blkSums, M);
    scatter_pairs<<<GB, 256, 0, stream>>>(src, dst, S, pairs, E);
    bucket_sort<<<BKT, 256, 0, stream>>>(pairs, S, off, csr_src, N, E);

    // ---- weight prep
    prep_w<<<96, 64, 0, stream>>>(W0, W1, W2, Wf);

    // ---- layer 0: t = bf16(x) @ W0
    gemm0<<<tileGrid, 256, 0, stream>>>(x, Wf, t, N);

    // ---- layer 1 (fused): t = relu(agg(t) + b0) @ W1
    agg_gemm_t<8, 128><<<tileGrid, 512, 0, stream>>>(t, off, csr_src, b0, Wf + 16384, t, N);

    // ---- layer 2 (fused): t2 = relu(agg(t) + b1) @ W2pad  (48 cols)
    agg_gemm_t<3, 48><<<tileGrid, 512, 0, stream>>>(t, off, csr_src, b1, Wf + 32768, t2, N);

    // ---- final: out = agg40(t2) + b2
    agg40b<<<aggGrid, 256, 0, stream>>>(t2, off, csr_src, b2, out, N);
}